// Round 6
// baseline (127.730 us; speedup 1.0000x reference)
//
#include <hip/hip_runtime.h>
#include <math.h>
#include <stdint.h>

#define D 4096
#define H 32
#define KVH 8
#define HD 128
#define B_ 8
#define SEQ 16
#define MAXLEN 2048
#define NTOK 128          // B_*SEQ
#define KSPLIT 16
#define KCH 256           // D / KSPLIT
#define BKW 32
#define WSTEPS (KCH / BKW) // 8
#define KSA 16            // attention key-split across blocks (merged by attn_merge)

typedef __attribute__((ext_vector_type(8))) short bh8;    // 8 bf16 (4 VGPRs)
typedef __attribute__((ext_vector_type(4))) float f32x4;  // MFMA C/D frag
typedef _Float16 f16x2 __attribute__((ext_vector_type(2)));
typedef _Float16 f16x8 __attribute__((ext_vector_type(8)));

static __device__ __forceinline__ int imin(int a, int b) { return a < b ? a : b; }

static __device__ __forceinline__ short f2bf(float x) {   // RNE f32 -> bf16 bits
    union { float f; uint32_t u; } v; v.f = x;
    uint32_t u = v.u;
    return (short)((u + 0x7fffu + ((u >> 16) & 1u)) >> 16);
}
static __device__ __forceinline__ float bf2f(short b) {
    union { uint32_t u; float f; } v; v.u = ((uint32_t)(uint16_t)b) << 16;
    return v.f;
}

static __device__ __forceinline__ float fexp2(float x) {
#if __has_builtin(__builtin_amdgcn_exp2f)
    return __builtin_amdgcn_exp2f(x);
#else
    return exp2f(x);
#endif
}

static __device__ __forceinline__ void gll16(const void* g, void* l) {
    __builtin_amdgcn_global_load_lds((const __attribute__((address_space(1))) uint32_t*)g,
                                     (__attribute__((address_space(3))) uint32_t*)l, 16, 0, 0);
}

// x (128 x 4096 f32) -> bf16 in MFMA A-layout: xp[(kg*128 + row)*8 + j], k = kg*8+j.
__global__ __launch_bounds__(256) void cvt_x(const float* __restrict__ x, short* __restrict__ xp) {
    int i = blockIdx.x * 256 + threadIdx.x;   // 131072 float4s
    int row = i >> 10;
    int c4 = (i & 1023) << 2;                 // col, multiple of 4
    const float4 v = ((const float4*)x)[i];
    short4 o;
    o.x = f2bf(v.x); o.y = f2bf(v.y); o.z = f2bf(v.z); o.w = f2bf(v.w);
    *(short4*)&xp[((size_t)((c4 >> 3) * 128 + row)) * 8 + (c4 & 7)] = o;
}

// C_partial(bf16) = A(128 x K bf16 pre-laid-out) @ W(K x ntot f32 row-major).
//
// v7 = v6 + COALESCED EPILOGUE (single-variable A/B vs r5).
// r5 post-mortem: QKV (97 MB HBM reads) and OP (80 MB, L3-served in r3) both
// take ~45 us across 5 structurally different read pipelines -> NOT read-BW
// capped. The round-invariant suspect: the epilogue wrote 64 scalar 2-B
// stores/thread (32-B fragments at 8-KB stride, ~25 MB of partial-line
// scattered writes bursted at kernel end). v7 keeps v6's streaming loop
// byte-identical and ONLY changes the epilogue: LDS-transpose (reusing the
// staging LDS after the final barrier - occupancy unchanged) then row-major
// short8 stores -> 512-B contiguous full-line runs per wave-store.
__global__ __launch_bounds__(512, 4) void gemm_wide(const short* __restrict__ xp,
                                                    const float* __restrict__ wq,
                                                    const float* __restrict__ wk,
                                                    const float* __restrict__ wv,
                                                    short* __restrict__ Pq,
                                                    short* __restrict__ Pk,
                                                    short* __restrict__ Pv) {
    const int cbid = blockIdx.x;
    const int ks = blockIdx.y;
    const float* W; short* P; int ntot; int cb;
    if (cbid < 16)      { W = wq; P = Pq; ntot = 4096; cb = cbid * 256; }
    else if (cbid < 20) { W = wk; P = Pk; ntot = 1024; cb = (cbid - 16) * 256; }
    else                { W = wv; P = Pv; ntot = 1024; cb = (cbid - 20) * 256; }
    const int tid = threadIdx.x;              // 0..511
    const int lane = tid & 63;
    const int wv_ = tid >> 6;                 // wave 0..7
    const int wm = wv_ >> 2, wn = wv_ & 3;    // wave tile: rows wm*64, cols wn*64
    const int lrow = lane & 15, lkg = lane >> 4;
    const int k0 = ks * KCH;
    const int kxor = (lkg & 1) << 4;          // read-side swizzle (dwords)

    __shared__ __align__(16) char smem[2][32768];     // Wt f32[32][256] per buf; CT overlay

    f32x4 acc[4][4];
#pragma unroll
    for (int fm = 0; fm < 4; ++fm)
#pragma unroll
        for (int fn = 0; fn < 4; ++fn) acc[fm][fn] = (f32x4){0.f, 0.f, 0.f, 0.f};

    // A: xp[((k0>>3 + t*4 + lkg)*128 + wm*64 + fm*16 + lrow)*8 + j]
    const short* abase = xp + ((size_t)((k0 >> 3) + lkg) * 128 + wm * 64 + lrow) * 8;

    // Stage one 32x256 f32 W-tile: 4 gll16 per thread; wave w, round r moves
    // row r*8+w as ONE contiguous 1KB transfer. Source chunk permuted by
    // xr=((row>>3)&1)<<2 so the ds_read below lands 2-way-conflict-free.
    auto stage = [&](int t, int bufw) {
        char* ldsb = smem[bufw];
#pragma unroll
        for (int r = 0; r < 4; ++r) {
            const int row = r * 8 + wv_;
            const int xr = (r & 1) << 2;
            const float* src = W + (size_t)(k0 + t * BKW + row) * ntot + cb + ((lane ^ xr) << 2);
            gll16(src, ldsb + r * 8192 + tid * 16);
        }
    };

    stage(0, 0);
    __syncthreads();

    int buf = 0;
    for (int t = 0; t < WSTEPS; ++t) {
        bh8 arr[4];
        {
            const short* p = abase + (size_t)t * 4096;   // t*4 kgroups * 128 rows * 8
#pragma unroll
            for (int fm = 0; fm < 4; ++fm)
                arr[fm] = *(const bh8*)(p + fm * 128);   // A issued FIRST (oldest)
        }
        if (t + 1 < WSTEPS) stage(t + 1, buf ^ 1);       // glls stay outstanding past A-wait
        const float* wb = (const float*)smem[buf];
#pragma unroll
        for (int fn = 0; fn < 4; ++fn) {
            const int col = wn * 64 + fn * 16 + lrow;
            bh8 bfr;
#pragma unroll
            for (int j = 0; j < 8; ++j)
                bfr[j] = f2bf(wb[(lkg * 8 + j) * 256 + (col ^ kxor)]);
#pragma unroll
            for (int fm = 0; fm < 4; ++fm)
                acc[fm][fn] = __builtin_amdgcn_mfma_f32_16x16x32_bf16(arr[fm], bfr, acc[fm][fn], 0, 0, 0);
        }
        __syncthreads();                                  // drains gll burst (m97 pattern)
        buf ^= 1;
    }

    // ---- Coalesced epilogue: LDS transpose (CT overlays smem[0], safe after
    // final barrier) then row-major 16-B stores: wave store = 4 rows x 512-B
    // contiguous runs (full cache lines), 8 dwordx4/thread vs 64 scalar b16.
    short (*CT)[264] = (short(*)[264])smem[0];            // 32 x 264 pad (bank-spread)
    short* pp = P + (size_t)ks * NTOK * ntot;
    const int rr = tid >> 4;                              // 0..31
    const int cc = (tid & 15) * 16;                       // 0..240
    const int gr_lo = (rr & 15) + (rr >> 4) * 64;         // row within fm-slab
#pragma unroll
    for (int fm = 0; fm < 4; ++fm) {
#pragma unroll
        for (int fn = 0; fn < 4; ++fn)
#pragma unroll
            for (int q = 0; q < 4; ++q)
                CT[wm * 16 + lkg * 4 + q][wn * 64 + fn * 16 + lrow] = f2bf(acc[fm][fn][q]);
        __syncthreads();
        const bh8 a0 = *(const bh8*)&CT[rr][cc];
        const bh8 a1 = *(const bh8*)&CT[rr][cc + 8];
        short* dst = pp + (size_t)(fm * 16 + gr_lo) * ntot + cb + cc;
        *(bh8*)dst = a0;
        *(bh8*)(dst + 8) = a1;
        __syncthreads();                                  // CT reused next fm
    }
}

// Sum K-split bf16 partials of Q/K/V; apply interleaved-pair rotary to q and k_new.
__global__ __launch_bounds__(256) void combine_rot(const short* __restrict__ Pq,
                                                   const short* __restrict__ Pk,
                                                   const short* __restrict__ Pv,
                                                   float* __restrict__ qb,
                                                   float* __restrict__ knb,
                                                   float* __restrict__ vnb,
                                                   const float* __restrict__ cosT,
                                                   const float* __restrict__ sinT,
                                                   const int* __restrict__ startp) {
    int gid = blockIdx.x * 256 + threadIdx.x;
    int tok = gid / 3072;
    int pr = gid % 3072;
    int col = pr * 2;
    int start = *startp;
    int pos = start + (tok & (SEQ - 1));
    float a = 0.f, b = 0.f;
    if (col < 4096) {
        const short* base = Pq + (size_t)tok * 4096 + col;
#pragma unroll
        for (int ks = 0; ks < KSPLIT; ++ks) {
            short2 t = *(const short2*)(base + (size_t)ks * NTOK * 4096);
            a += bf2f(t.x); b += bf2f(t.y);
        }
        int i = (col & 127) >> 1;
        float c = cosT[pos * 64 + i], s = sinT[pos * 64 + i];
        qb[(size_t)tok * 4096 + col]     = a * c - b * s;
        qb[(size_t)tok * 4096 + col + 1] = a * s + b * c;
    } else if (col < 5120) {
        int colr = col - 4096;
        const short* base = Pk + (size_t)tok * 1024 + colr;
#pragma unroll
        for (int ks = 0; ks < KSPLIT; ++ks) {
            short2 t = *(const short2*)(base + (size_t)ks * NTOK * 1024);
            a += bf2f(t.x); b += bf2f(t.y);
        }
        int i = (colr & 127) >> 1;
        float c = cosT[pos * 64 + i], s = sinT[pos * 64 + i];
        knb[(size_t)tok * 1024 + colr]     = a * c - b * s;
        knb[(size_t)tok * 1024 + colr + 1] = a * s + b * c;
    } else {
        int colr = col - 5120;
        const short* base = Pv + (size_t)tok * 1024 + colr;
#pragma unroll
        for (int ks = 0; ks < KSPLIT; ++ks) {
            short2 t = *(const short2*)(base + (size_t)ks * NTOK * 1024);
            a += bf2f(t.x); b += bf2f(t.y);
        }
        vnb[(size_t)tok * 1024 + colr]     = a;
        vnb[(size_t)tok * 1024 + colr + 1] = b;
    }
}

// MFMA attention partial pass. grid (ksb, kvh, b) = (16,8,8); block = 256 = 4 waves.
__global__ __launch_bounds__(256) void attn_fused(const float* __restrict__ qb,
                                                  const float* __restrict__ knb,
                                                  const float* __restrict__ vnb,
                                                  const float* __restrict__ ck,
                                                  const float* __restrict__ cv,
                                                  short* __restrict__ Opart,
                                                  float* __restrict__ mpart,
                                                  float* __restrict__ lpart,
                                                  const int* __restrict__ startp) {
    const int ksb = blockIdx.x;
    const int kvh = blockIdx.y;
    const int b   = blockIdx.z;
    const int start = *startp;
    const int klen = start + SEQ;
    const int chunk = (klen + KSA - 1) / KSA;        // 65
    const int bbeg = ksb * chunk;
    const int bend = imin(bbeg + chunk, klen);
    const int tiles = (chunk + 31) >> 5;             // 3, uniform across waves/blocks

    const int tid = threadIdx.x;
    const int w = tid >> 6, lane = tid & 63;
    const int c = lane & 15, g = lane >> 4;
    const int hh = kvh * 4 + w;

    __shared__ __align__(16) _Float16 Ksh[2][16][32][8];   // [buf][dg][slot][8] 16KB
    __shared__ __align__(16) _Float16 Vsh[2][4][128][8];   // [buf][kg][d][key&7] 16KB

    const float scl2 = 0.08838834764831843f * 1.4426950408889634f;  // 1/sqrt(128)*log2e

    f16x8 qfr[4];
    {
        const float* qp = qb + (size_t)(b * SEQ + c) * 4096 + hh * 128 + 8 * g;
#pragma unroll
        for (int h = 0; h < 4; ++h) {
            float4 a = *(const float4*)(qp + 32 * h);
            float4 b2 = *(const float4*)(qp + 32 * h + 4);
            qfr[h][0] = (_Float16)(a.x * scl2);  qfr[h][1] = (_Float16)(a.y * scl2);
            qfr[h][2] = (_Float16)(a.z * scl2);  qfr[h][3] = (_Float16)(a.w * scl2);
            qfr[h][4] = (_Float16)(b2.x * scl2); qfr[h][5] = (_Float16)(b2.y * scl2);
            qfr[h][6] = (_Float16)(b2.z * scl2); qfr[h][7] = (_Float16)(b2.w * scl2);
        }
    }

    f32x4 acc_o[8];
#pragma unroll
    for (int dm = 0; dm < 8; ++dm) acc_o[dm] = (f32x4){0.f, 0.f, 0.f, 0.f};
    float mrun = -INFINITY, lrun = 0.f;

    const int s_   = tid & 31;
    const int dgA  = tid >> 5;             // 0..7
    const int koffK = 8 * ((s_ >> 2) & 3) + 4 * (s_ >> 4) + (s_ & 3);
    const int kg0 = tid >> 6, d0 = (tid & 63) * 2;

    float4 kr0, kr1, kr2, kr3;
    float2 vrw[8];
    auto gloadRaw = [&](int t) {
        const int kp = bbeg + t * 32 + koffK;
        kr0 = (float4){0.f,0.f,0.f,0.f}; kr1 = kr0; kr2 = kr0; kr3 = kr0;
        if (kp < bend) {
            const float* kr = (kp < start)
                ? ck + ((size_t)((b * MAXLEN + kp) * KVH + kvh)) * HD
                : knb + (size_t)(b * SEQ + kp - start) * 1024 + kvh * HD;
            kr0 = *(const float4*)(kr + dgA * 8);
            kr1 = *(const float4*)(kr + dgA * 8 + 4);
            kr2 = *(const float4*)(kr + dgA * 8 + 64);
            kr3 = *(const float4*)(kr + dgA * 8 + 68);
        }
#pragma unroll
        for (int j = 0; j < 8; ++j) {
            const int kpv = bbeg + t * 32 + kg0 * 8 + j;
            vrw[j] = (float2){0.f, 0.f};
            if (kpv < bend) {
                const float* vrp = (kpv < start)
                    ? cv + ((size_t)((b * MAXLEN + kpv) * KVH + kvh)) * HD + d0
                    : vnb + (size_t)(b * SEQ + kpv - start) * 1024 + kvh * HD + d0;
                vrw[j] = *(const float2*)vrp;
            }
        }
    };
    auto cvtStore = [&](int bf) {
        f16x8 ka, kb;
        ka[0]=(_Float16)kr0.x; ka[1]=(_Float16)kr0.y; ka[2]=(_Float16)kr0.z; ka[3]=(_Float16)kr0.w;
        ka[4]=(_Float16)kr1.x; ka[5]=(_Float16)kr1.y; ka[6]=(_Float16)kr1.z; ka[7]=(_Float16)kr1.w;
        kb[0]=(_Float16)kr2.x; kb[1]=(_Float16)kr2.y; kb[2]=(_Float16)kr2.z; kb[3]=(_Float16)kr2.w;
        kb[4]=(_Float16)kr3.x; kb[5]=(_Float16)kr3.y; kb[6]=(_Float16)kr3.z; kb[7]=(_Float16)kr3.w;
        *(f16x8*)&Ksh[bf][dgA][s_][0] = ka;
        *(f16x8*)&Ksh[bf][dgA + 8][s_][0] = kb;
        f16x8 w0, w1;
#pragma unroll
        for (int j = 0; j < 8; ++j) { w0[j] = (_Float16)vrw[j].x; w1[j] = (_Float16)vrw[j].y; }
        *(f16x8*)&Vsh[bf][kg0][d0][0] = w0;
        *(f16x8*)&Vsh[bf][kg0][d0 + 1][0] = w1;
    };

    gloadRaw(0);
    cvtStore(0);
    __syncthreads();

    int buf = 0;
    for (int t = 0; t < tiles; ++t) {
        if (t + 1 < tiles) gloadRaw(t + 1);
        const int nk = imin(32, bend - (bbeg + t * 32));

        f32x4 acc_s[2];
        acc_s[0] = (f32x4){0.f, 0.f, 0.f, 0.f};
        acc_s[1] = (f32x4){0.f, 0.f, 0.f, 0.f};
#pragma unroll
        for (int h = 0; h < 4; ++h) {
#pragma unroll
            for (int m = 0; m < 2; ++m) {
                const f16x8 afr = *(const f16x8*)&Ksh[buf][h * 4 + g][m * 16 + c][0];
                acc_s[m] = __builtin_amdgcn_mfma_f32_16x16x32_f16(afr, qfr[h], acc_s[m], 0, 0, 0);
            }
        }
        float s8[8];
#pragma unroll
        for (int m = 0; m < 2; ++m)
#pragma unroll
            for (int q = 0; q < 4; ++q) s8[m * 4 + q] = acc_s[m][q];
        if (nk < 32) {
#pragma unroll
            for (int jj = 0; jj < 8; ++jj)
                if (8 * g + jj >= nk) s8[jj] = -1e30f;
        }
        float tmax = s8[0];
#pragma unroll
        for (int jj = 1; jj < 8; ++jj) tmax = fmaxf(tmax, s8[jj]);
        tmax = fmaxf(tmax, __shfl_xor(tmax, 16));
        tmax = fmaxf(tmax, __shfl_xor(tmax, 32));
        if (__any(tmax > mrun + 11.5f)) {
            const float mn = fmaxf(mrun, tmax);
            const float fac = fexp2(mrun - mn);
            lrun *= fac;
#pragma unroll
            for (int dm = 0; dm < 8; ++dm) {
                acc_o[dm][0] *= fac; acc_o[dm][1] *= fac;
                acc_o[dm][2] *= fac; acc_o[dm][3] *= fac;
            }
            mrun = mn;
        }
        float pe[8];
#pragma unroll
        for (int jj = 0; jj < 8; ++jj) pe[jj] = fexp2(s8[jj] - mrun);
#pragma unroll
        for (int jj = 0; jj < 8; ++jj) lrun += pe[jj];
        f16x8 bp;
#pragma unroll
        for (int jj = 0; jj < 8; ++jj) bp[jj] = (_Float16)pe[jj];

#pragma unroll
        for (int dm = 0; dm < 8; ++dm) {
            const f16x8 av = *(const f16x8*)&Vsh[buf][g][dm * 16 + c][0];
            acc_o[dm] = __builtin_amdgcn_mfma_f32_16x16x32_f16(av, bp, acc_o[dm], 0, 0, 0);
        }

        if (t + 1 < tiles) cvtStore(buf ^ 1);
        __syncthreads();
        buf ^= 1;
    }

    lrun += __shfl_xor(lrun, 16);
    lrun += __shfl_xor(lrun, 32);

    const int base = ((b * KVH + kvh) * KSA + ksb) * 64;
    const int row = w * 16 + c;
#pragma unroll
    for (int dm = 0; dm < 8; ++dm) {
        short4 o4;
        o4.x = f2bf(acc_o[dm][0]); o4.y = f2bf(acc_o[dm][1]);
        o4.z = f2bf(acc_o[dm][2]); o4.w = f2bf(acc_o[dm][3]);
        *(short4*)&Opart[(size_t)(base + row) * 128 + dm * 16 + g * 4] = o4;
    }
    if (g == 0) { mpart[base + row] = mrun; lpart[base + row] = lrun; }
}

// Merge KSA partials -> aob (bf16, out-proj A-layout). m/l are exp2-domain.
__global__ __launch_bounds__(256) void attn_merge(const short* __restrict__ Opart,
                                                  const float* __restrict__ mpart,
                                                  const float* __restrict__ lpart,
                                                  short* __restrict__ aob) {
    const int bkvh = blockIdx.x;
    const int tid = threadIdx.x;
    __shared__ float sf[KSA][64];
    __shared__ float sinvL[64];
    if (tid < 64) {
        const int row = tid;
        float M = -INFINITY;
#pragma unroll
        for (int ks = 0; ks < KSA; ++ks)
            M = fmaxf(M, mpart[(size_t)(bkvh * KSA + ks) * 64 + row]);
        float L = 0.f;
#pragma unroll
        for (int ks = 0; ks < KSA; ++ks) {
            float f = exp2f(mpart[(size_t)(bkvh * KSA + ks) * 64 + row] - M);
            sf[ks][row] = f;
            L += f * lpart[(size_t)(bkvh * KSA + ks) * 64 + row];
        }
        sinvL[row] = 1.f / L;
    }
    __syncthreads();
    const int b = bkvh >> 3, kvh = bkvh & 7;
    for (int e = tid; e < 2048; e += 256) {
        const int row = e >> 5;
        const int d4 = (e & 31) << 2;
        float a0 = 0.f, a1 = 0.f, a2 = 0.f, a3 = 0.f;
#pragma unroll
        for (int ks = 0; ks < KSA; ++ks) {
            const short4 sp = *(const short4*)&Opart[((size_t)(bkvh * KSA + ks) * 64 + row) * 128 + d4];
            const float f = sf[ks][row];
            a0 = fmaf(f, bf2f(sp.x), a0);
            a1 = fmaf(f, bf2f(sp.y), a1);
            a2 = fmaf(f, bf2f(sp.z), a2);
            a3 = fmaf(f, bf2f(sp.w), a3);
        }
        const float iL = sinvL[row];
        a0 *= iL; a1 *= iL; a2 *= iL; a3 *= iL;
        const int hh = kvh * 4 + (row >> 4);
        const int tok = b * SEQ + (row & 15);
        const int col = hh * 128 + d4;
        short4 o;
        o.x = f2bf(a0); o.y = f2bf(a1); o.z = f2bf(a2); o.w = f2bf(a3);
        *(short4*)&aob[((size_t)(col >> 3) * 128 + tok) * 8 + (col & 7)] = o;
    }
}

// Sum the KSPLIT bf16 out-proj partials into f32 d_out.
__global__ __launch_bounds__(256) void sum_parts(const short* __restrict__ P,
                                                 float* __restrict__ out) {
    int i = blockIdx.x * 256 + threadIdx.x;     // over groups of 4 elems, 131072 total
    float a0 = 0.f, a1 = 0.f, a2 = 0.f, a3 = 0.f;
#pragma unroll
    for (int ks = 0; ks < KSPLIT; ++ks) {
        const short4 t = ((const short4*)(P + (size_t)ks * NTOK * 4096))[i];
        a0 += bf2f(t.x); a1 += bf2f(t.y); a2 += bf2f(t.z); a3 += bf2f(t.w);
    }
    ((float4*)out)[i] = make_float4(a0, a1, a2, a3);
}

extern "C" void kernel_launch(void* const* d_in, const int* in_sizes, int n_in,
                              void* d_out, int out_size, void* d_ws, size_t ws_size,
                              hipStream_t stream) {
    const float* x  = (const float*)d_in[0];
    const float* wq = (const float*)d_in[1];
    const float* wk = (const float*)d_in[2];
    const float* wv = (const float*)d_in[3];
    const float* wo = (const float*)d_in[4];
    const float* cs = (const float*)d_in[5];
    const float* sn = (const float*)d_in[6];
    const float* ck = (const float*)d_in[7];
    const float* cv = (const float*)d_in[8];
    const int* startp = (const int*)d_in[9];

    // ws layout. Pqb (16.78MB) == Opart size exactly; Opart overlays Pqb
    // (Pq dead after combine_rot, Opart dead before out-proj writes Pqb).
    short* Pqb = (short*)d_ws;                                // KSPLIT*NTOK*4096
    short* Pkb = Pqb + (size_t)KSPLIT * NTOK * 4096;
    short* Pvb = Pkb + (size_t)KSPLIT * NTOK * 1024;
    short* Opart = Pqb;                                       // overlay
    float* qb   = (float*)(Pvb + (size_t)KSPLIT * NTOK * 1024);
    float* knb  = qb + (size_t)NTOK * 4096;
    float* vnb  = knb + (size_t)NTOK * 1024;
    short* xpre = (short*)(vnb + (size_t)NTOK * 1024);
    short* aob  = xpre + (size_t)NTOK * 4096;
    float* mpart = (float*)(aob + (size_t)NTOK * 4096);
    float* lpart = mpart + (size_t)64 * KSA * 64;
    // total ws ~31MB

    cvt_x<<<512, 256, 0, stream>>>(x, xpre);
    // QKV: 16 Q + 4 K + 4 V col-blocks (NT=256), x KSPLIT=16 -> 384 blocks
    gemm_wide<<<dim3(24, KSPLIT), 512, 0, stream>>>(xpre, wq, wk, wv, Pqb, Pkb, Pvb);
    combine_rot<<<1536, 256, 0, stream>>>(Pqb, Pkb, Pvb, qb, knb, vnb, cs, sn, startp);
    attn_fused<<<dim3(KSA, KVH, B_), 256, 0, stream>>>(qb, knb, vnb, ck, cv, Opart, mpart, lpart, startp);
    attn_merge<<<64, 256, 0, stream>>>(Opart, mpart, lpart, aob);
    // out-proj: 16 col-blocks x KSPLIT=16 -> 256 blocks (1/CU), Q-branch (W=wo)
    gemm_wide<<<dim3(16, KSPLIT), 512, 0, stream>>>(aob, wo, wo, wo, Pqb, Pqb, Pqb);
    sum_parts<<<512, 256, 0, stream>>>(Pqb, (float*)d_out);
}

// Round 7
// 124.162 us; speedup vs baseline: 1.0287x; 1.0287x over previous
//
#include <hip/hip_runtime.h>
#include <math.h>
#include <stdint.h>

#define D 4096
#define H 32
#define KVH 8
#define HD 128
#define B_ 8
#define SEQ 16
#define MAXLEN 2048
#define NTOK 128          // B_*SEQ
#define KSPLIT 16
#define KCH 256           // D / KSPLIT
#define BK 32
#define TSTEPS (KCH / BK) // 8
#define KSA 16            // attention key-split across blocks (merged by attn_merge)

typedef __attribute__((ext_vector_type(8))) short bh8;    // 8 bf16 (4 VGPRs)
typedef __attribute__((ext_vector_type(4))) float f32x4;  // MFMA C/D frag
typedef _Float16 f16x2 __attribute__((ext_vector_type(2)));
typedef _Float16 f16x8 __attribute__((ext_vector_type(8)));

static __device__ __forceinline__ int imin(int a, int b) { return a < b ? a : b; }

static __device__ __forceinline__ short f2bf(float x) {   // RNE f32 -> bf16 bits
    union { float f; uint32_t u; } v; v.f = x;
    uint32_t u = v.u;
    return (short)((u + 0x7fffu + ((u >> 16) & 1u)) >> 16);
}
static __device__ __forceinline__ float bf2f(short b) {
    union { uint32_t u; float f; } v; v.u = ((uint32_t)(uint16_t)b) << 16;
    return v.f;
}

static __device__ __forceinline__ float fexp2(float x) {
#if __has_builtin(__builtin_amdgcn_exp2f)
    return __builtin_amdgcn_exp2f(x);
#else
    return exp2f(x);
#endif
}

// x (128 x 4096 f32) -> bf16 in MFMA A-layout: xp[(kg*128 + row)*8 + j], k = kg*8+j.
__global__ __launch_bounds__(256) void cvt_x(const float* __restrict__ x, short* __restrict__ xp) {
    int i = blockIdx.x * 256 + threadIdx.x;   // 131072 float4s
    int row = i >> 10;
    int c4 = (i & 1023) << 2;                 // col, multiple of 4
    const float4 v = ((const float4*)x)[i];
    short4 o;
    o.x = f2bf(v.x); o.y = f2bf(v.y); o.z = f2bf(v.z); o.w = f2bf(v.w);
    *(short4*)&xp[((size_t)((c4 >> 3) * 128 + row)) * 8 + (c4 & 7)] = o;
}

// C_partial(bf16) = A(128 x K, bf16 pre-laid-out) @ W(K x ntot, f32 row-major).
//
// v8 = r2's v3 reg-direct GEMM with DOUBLED CONCURRENCY (single-lever A/B).
// r0-r6 post-mortem: six structurally different pipelines (LDS/reg, narrow/
// wide, barriered/barrier-free, gll/flat) ALL launched exactly 12 waves/CU
// (QKV) and 8 waves/CU (OP) and ALL served ~8.2 MB per wave-per-CU in ~44 us
// -> duration is set by resident-wave count, not bytes or structure:
// latency-bound, grid-limited. VGPR=64 permits 32 waves/CU; grid never
// supplied more than 12. Fix: KSPLIT 8->16 -> QKV 1536 blocks (24 waves/CU),
// OP 1024 blocks (16 waves/CU). Kernel body unchanged from v3.
__global__ __launch_bounds__(256) void gemm_mfma(const short* __restrict__ xp,
                                                 const float* __restrict__ wq,
                                                 const float* __restrict__ wk,
                                                 const float* __restrict__ wv,
                                                 short* __restrict__ Pq,
                                                 short* __restrict__ Pk,
                                                 short* __restrict__ Pv) {
    const int cbid = blockIdx.x;
    const int ks = blockIdx.y;
    const float* W; short* P; int ntot; int cb;
    if (cbid < 64)      { W = wq; P = Pq; ntot = 4096; cb = cbid * 64; }
    else if (cbid < 80) { W = wk; P = Pk; ntot = 1024; cb = (cbid - 64) * 64; }
    else                { W = wv; P = Pv; ntot = 1024; cb = (cbid - 80) * 64; }
    const int tid = threadIdx.x;              // 0..255
    const int lane = tid & 63;
    const int w = tid >> 6;                   // wave 0..3
    const int wm = w >> 1, wn = w & 1;        // wave tile: rows wm*64, cols wn*32
    const int lrow = lane & 15, lkg = lane >> 4;
    const int k0 = ks * KCH;

    f32x4 acc[4][2];
#pragma unroll
    for (int fm = 0; fm < 4; ++fm)
#pragma unroll
        for (int fn = 0; fn < 2; ++fn) acc[fm][fn] = (f32x4){0.f, 0.f, 0.f, 0.f};

    // A: xp[(( (k0>>3) + t*4 + lkg )*128 + wm*64 + fm*16 + lrow)*8 + j]
    const short* abase = xp + ((size_t)((k0 >> 3) + lkg) * 128 + wm * 64 + lrow) * 8;
    // W: W[(k0 + t*32 + lkg*8 + j)*ntot + cb + wn*32 + fn*16 + lrow]
    const float* wbase = W + (size_t)(k0 + lkg * 8) * ntot + cb + wn * 32 + lrow;

    auto loadWf = [&](int t, float (&wr)[16]) {
        const float* p = wbase + (size_t)t * 32 * ntot;
#pragma unroll
        for (int j = 0; j < 8; ++j) {
            wr[j]     = p[0];    // fn = 0
            wr[8 + j] = p[16];   // fn = 1
            p += ntot;
        }
    };
    auto loadAf = [&](int t, bh8 (&ar)[4]) {
        const short* p = abase + (size_t)t * 4096;   // t*4 kgroups * 128 rows * 8
#pragma unroll
        for (int fm = 0; fm < 4; ++fm)
            ar[fm] = *(const bh8*)(p + fm * 128);
    };
    auto comp = [&](const bh8 (&ar)[4], const float (&wr)[16]) {
        bh8 bf0, bf1;
#pragma unroll
        for (int j = 0; j < 8; ++j) { bf0[j] = f2bf(wr[j]); bf1[j] = f2bf(wr[8 + j]); }
#pragma unroll
        for (int fm = 0; fm < 4; ++fm) {
            acc[fm][0] = __builtin_amdgcn_mfma_f32_16x16x32_bf16(ar[fm], bf0, acc[fm][0], 0, 0, 0);
            acc[fm][1] = __builtin_amdgcn_mfma_f32_16x16x32_bf16(ar[fm], bf1, acc[fm][1], 0, 0, 0);
        }
    };

    float wr0[16], wr1[16];
    bh8 ar0[4], ar1[4];
    loadWf(0, wr0); loadAf(0, ar0);
    for (int t = 0; t < TSTEPS; t += 2) {
        loadWf(t + 1, wr1); loadAf(t + 1, ar1);    // stage t+1 in flight under comp(t)
        comp(ar0, wr0);
        if (t + 2 < TSTEPS) { loadWf(t + 2, wr0); loadAf(t + 2, ar0); }
        comp(ar1, wr1);
    }

    short* pp = P + (size_t)ks * NTOK * ntot;
#pragma unroll
    for (int fm = 0; fm < 4; ++fm) {
        const int gr0 = wm * 64 + fm * 16 + lkg * 4;
#pragma unroll
        for (int fn = 0; fn < 2; ++fn) {
            const int gc = cb + wn * 32 + fn * 16 + lrow;
#pragma unroll
            for (int q = 0; q < 4; ++q)
                pp[(size_t)(gr0 + q) * ntot + gc] = f2bf(acc[fm][fn][q]);
        }
    }
}

// Sum K-split bf16 partials of Q/K/V; apply interleaved-pair rotary to q and k_new.
__global__ __launch_bounds__(256) void combine_rot(const short* __restrict__ Pq,
                                                   const short* __restrict__ Pk,
                                                   const short* __restrict__ Pv,
                                                   float* __restrict__ qb,
                                                   float* __restrict__ knb,
                                                   float* __restrict__ vnb,
                                                   const float* __restrict__ cosT,
                                                   const float* __restrict__ sinT,
                                                   const int* __restrict__ startp) {
    int gid = blockIdx.x * 256 + threadIdx.x;
    int tok = gid / 3072;
    int pr = gid % 3072;
    int col = pr * 2;
    int start = *startp;
    int pos = start + (tok & (SEQ - 1));
    float a = 0.f, b = 0.f;
    if (col < 4096) {
        const short* base = Pq + (size_t)tok * 4096 + col;
#pragma unroll
        for (int ks = 0; ks < KSPLIT; ++ks) {
            short2 t = *(const short2*)(base + (size_t)ks * NTOK * 4096);
            a += bf2f(t.x); b += bf2f(t.y);
        }
        int i = (col & 127) >> 1;
        float c = cosT[pos * 64 + i], s = sinT[pos * 64 + i];
        qb[(size_t)tok * 4096 + col]     = a * c - b * s;
        qb[(size_t)tok * 4096 + col + 1] = a * s + b * c;
    } else if (col < 5120) {
        int colr = col - 4096;
        const short* base = Pk + (size_t)tok * 1024 + colr;
#pragma unroll
        for (int ks = 0; ks < KSPLIT; ++ks) {
            short2 t = *(const short2*)(base + (size_t)ks * NTOK * 1024);
            a += bf2f(t.x); b += bf2f(t.y);
        }
        int i = (colr & 127) >> 1;
        float c = cosT[pos * 64 + i], s = sinT[pos * 64 + i];
        knb[(size_t)tok * 1024 + colr]     = a * c - b * s;
        knb[(size_t)tok * 1024 + colr + 1] = a * s + b * c;
    } else {
        int colr = col - 5120;
        const short* base = Pv + (size_t)tok * 1024 + colr;
#pragma unroll
        for (int ks = 0; ks < KSPLIT; ++ks) {
            short2 t = *(const short2*)(base + (size_t)ks * NTOK * 1024);
            a += bf2f(t.x); b += bf2f(t.y);
        }
        vnb[(size_t)tok * 1024 + colr]     = a;
        vnb[(size_t)tok * 1024 + colr + 1] = b;
    }
}

// MFMA attention partial pass. grid (ksb, kvh, b) = (16,8,8); block = 256 = 4 waves.
__global__ __launch_bounds__(256) void attn_fused(const float* __restrict__ qb,
                                                  const float* __restrict__ knb,
                                                  const float* __restrict__ vnb,
                                                  const float* __restrict__ ck,
                                                  const float* __restrict__ cv,
                                                  short* __restrict__ Opart,
                                                  float* __restrict__ mpart,
                                                  float* __restrict__ lpart,
                                                  const int* __restrict__ startp) {
    const int ksb = blockIdx.x;
    const int kvh = blockIdx.y;
    const int b   = blockIdx.z;
    const int start = *startp;
    const int klen = start + SEQ;
    const int chunk = (klen + KSA - 1) / KSA;        // 65
    const int bbeg = ksb * chunk;
    const int bend = imin(bbeg + chunk, klen);
    const int tiles = (chunk + 31) >> 5;             // 3, uniform across waves/blocks

    const int tid = threadIdx.x;
    const int w = tid >> 6, lane = tid & 63;
    const int c = lane & 15, g = lane >> 4;
    const int hh = kvh * 4 + w;

    __shared__ __align__(16) _Float16 Ksh[2][16][32][8];   // [buf][dg][slot][8] 16KB
    __shared__ __align__(16) _Float16 Vsh[2][4][128][8];   // [buf][kg][d][key&7] 16KB

    const float scl2 = 0.08838834764831843f * 1.4426950408889634f;  // 1/sqrt(128)*log2e

    f16x8 qfr[4];
    {
        const float* qp = qb + (size_t)(b * SEQ + c) * 4096 + hh * 128 + 8 * g;
#pragma unroll
        for (int h = 0; h < 4; ++h) {
            float4 a = *(const float4*)(qp + 32 * h);
            float4 b2 = *(const float4*)(qp + 32 * h + 4);
            qfr[h][0] = (_Float16)(a.x * scl2);  qfr[h][1] = (_Float16)(a.y * scl2);
            qfr[h][2] = (_Float16)(a.z * scl2);  qfr[h][3] = (_Float16)(a.w * scl2);
            qfr[h][4] = (_Float16)(b2.x * scl2); qfr[h][5] = (_Float16)(b2.y * scl2);
            qfr[h][6] = (_Float16)(b2.z * scl2); qfr[h][7] = (_Float16)(b2.w * scl2);
        }
    }

    f32x4 acc_o[8];
#pragma unroll
    for (int dm = 0; dm < 8; ++dm) acc_o[dm] = (f32x4){0.f, 0.f, 0.f, 0.f};
    float mrun = -INFINITY, lrun = 0.f;

    const int s_   = tid & 31;
    const int dgA  = tid >> 5;             // 0..7
    const int koffK = 8 * ((s_ >> 2) & 3) + 4 * (s_ >> 4) + (s_ & 3);
    const int kg0 = tid >> 6, d0 = (tid & 63) * 2;

    float4 kr0, kr1, kr2, kr3;
    float2 vrw[8];
    auto gloadRaw = [&](int t) {
        const int kp = bbeg + t * 32 + koffK;
        kr0 = (float4){0.f,0.f,0.f,0.f}; kr1 = kr0; kr2 = kr0; kr3 = kr0;
        if (kp < bend) {
            const float* kr = (kp < start)
                ? ck + ((size_t)((b * MAXLEN + kp) * KVH + kvh)) * HD
                : knb + (size_t)(b * SEQ + kp - start) * 1024 + kvh * HD;
            kr0 = *(const float4*)(kr + dgA * 8);
            kr1 = *(const float4*)(kr + dgA * 8 + 4);
            kr2 = *(const float4*)(kr + dgA * 8 + 64);
            kr3 = *(const float4*)(kr + dgA * 8 + 68);
        }
#pragma unroll
        for (int j = 0; j < 8; ++j) {
            const int kpv = bbeg + t * 32 + kg0 * 8 + j;
            vrw[j] = (float2){0.f, 0.f};
            if (kpv < bend) {
                const float* vrp = (kpv < start)
                    ? cv + ((size_t)((b * MAXLEN + kpv) * KVH + kvh)) * HD + d0
                    : vnb + (size_t)(b * SEQ + kpv - start) * 1024 + kvh * HD + d0;
                vrw[j] = *(const float2*)vrp;
            }
        }
    };
    auto cvtStore = [&](int bf) {
        f16x8 ka, kb;
        ka[0]=(_Float16)kr0.x; ka[1]=(_Float16)kr0.y; ka[2]=(_Float16)kr0.z; ka[3]=(_Float16)kr0.w;
        ka[4]=(_Float16)kr1.x; ka[5]=(_Float16)kr1.y; ka[6]=(_Float16)kr1.z; ka[7]=(_Float16)kr1.w;
        kb[0]=(_Float16)kr2.x; kb[1]=(_Float16)kr2.y; kb[2]=(_Float16)kr2.z; kb[3]=(_Float16)kr2.w;
        kb[4]=(_Float16)kr3.x; kb[5]=(_Float16)kr3.y; kb[6]=(_Float16)kr3.z; kb[7]=(_Float16)kr3.w;
        *(f16x8*)&Ksh[bf][dgA][s_][0] = ka;
        *(f16x8*)&Ksh[bf][dgA + 8][s_][0] = kb;
        f16x8 w0, w1;
#pragma unroll
        for (int j = 0; j < 8; ++j) { w0[j] = (_Float16)vrw[j].x; w1[j] = (_Float16)vrw[j].y; }
        *(f16x8*)&Vsh[bf][kg0][d0][0] = w0;
        *(f16x8*)&Vsh[bf][kg0][d0 + 1][0] = w1;
    };

    gloadRaw(0);
    cvtStore(0);
    __syncthreads();

    int buf = 0;
    for (int t = 0; t < tiles; ++t) {
        if (t + 1 < tiles) gloadRaw(t + 1);
        const int nk = imin(32, bend - (bbeg + t * 32));

        f32x4 acc_s[2];
        acc_s[0] = (f32x4){0.f, 0.f, 0.f, 0.f};
        acc_s[1] = (f32x4){0.f, 0.f, 0.f, 0.f};
#pragma unroll
        for (int h = 0; h < 4; ++h) {
#pragma unroll
            for (int m = 0; m < 2; ++m) {
                const f16x8 afr = *(const f16x8*)&Ksh[buf][h * 4 + g][m * 16 + c][0];
                acc_s[m] = __builtin_amdgcn_mfma_f32_16x16x32_f16(afr, qfr[h], acc_s[m], 0, 0, 0);
            }
        }
        float s8[8];
#pragma unroll
        for (int m = 0; m < 2; ++m)
#pragma unroll
            for (int q = 0; q < 4; ++q) s8[m * 4 + q] = acc_s[m][q];
        if (nk < 32) {
#pragma unroll
            for (int jj = 0; jj < 8; ++jj)
                if (8 * g + jj >= nk) s8[jj] = -1e30f;
        }
        float tmax = s8[0];
#pragma unroll
        for (int jj = 1; jj < 8; ++jj) tmax = fmaxf(tmax, s8[jj]);
        tmax = fmaxf(tmax, __shfl_xor(tmax, 16));
        tmax = fmaxf(tmax, __shfl_xor(tmax, 32));
        if (__any(tmax > mrun + 11.5f)) {
            const float mn = fmaxf(mrun, tmax);
            const float fac = fexp2(mrun - mn);
            lrun *= fac;
#pragma unroll
            for (int dm = 0; dm < 8; ++dm) {
                acc_o[dm][0] *= fac; acc_o[dm][1] *= fac;
                acc_o[dm][2] *= fac; acc_o[dm][3] *= fac;
            }
            mrun = mn;
        }
        float pe[8];
#pragma unroll
        for (int jj = 0; jj < 8; ++jj) pe[jj] = fexp2(s8[jj] - mrun);
#pragma unroll
        for (int jj = 0; jj < 8; ++jj) lrun += pe[jj];
        f16x8 bp;
#pragma unroll
        for (int jj = 0; jj < 8; ++jj) bp[jj] = (_Float16)pe[jj];

#pragma unroll
        for (int dm = 0; dm < 8; ++dm) {
            const f16x8 av = *(const f16x8*)&Vsh[buf][g][dm * 16 + c][0];
            acc_o[dm] = __builtin_amdgcn_mfma_f32_16x16x32_f16(av, bp, acc_o[dm], 0, 0, 0);
        }

        if (t + 1 < tiles) cvtStore(buf ^ 1);
        __syncthreads();
        buf ^= 1;
    }

    lrun += __shfl_xor(lrun, 16);
    lrun += __shfl_xor(lrun, 32);

    const int base = ((b * KVH + kvh) * KSA + ksb) * 64;
    const int row = w * 16 + c;
#pragma unroll
    for (int dm = 0; dm < 8; ++dm) {
        short4 o4;
        o4.x = f2bf(acc_o[dm][0]); o4.y = f2bf(acc_o[dm][1]);
        o4.z = f2bf(acc_o[dm][2]); o4.w = f2bf(acc_o[dm][3]);
        *(short4*)&Opart[(size_t)(base + row) * 128 + dm * 16 + g * 4] = o4;
    }
    if (g == 0) { mpart[base + row] = mrun; lpart[base + row] = lrun; }
}

// Merge KSA partials -> aob (bf16, out-proj A-layout). m/l are exp2-domain.
__global__ __launch_bounds__(256) void attn_merge(const short* __restrict__ Opart,
                                                  const float* __restrict__ mpart,
                                                  const float* __restrict__ lpart,
                                                  short* __restrict__ aob) {
    const int bkvh = blockIdx.x;
    const int tid = threadIdx.x;
    __shared__ float sf[KSA][64];
    __shared__ float sinvL[64];
    if (tid < 64) {
        const int row = tid;
        float M = -INFINITY;
#pragma unroll
        for (int ks = 0; ks < KSA; ++ks)
            M = fmaxf(M, mpart[(size_t)(bkvh * KSA + ks) * 64 + row]);
        float L = 0.f;
#pragma unroll
        for (int ks = 0; ks < KSA; ++ks) {
            float f = exp2f(mpart[(size_t)(bkvh * KSA + ks) * 64 + row] - M);
            sf[ks][row] = f;
            L += f * lpart[(size_t)(bkvh * KSA + ks) * 64 + row];
        }
        sinvL[row] = 1.f / L;
    }
    __syncthreads();
    const int b = bkvh >> 3, kvh = bkvh & 7;
    for (int e = tid; e < 2048; e += 256) {
        const int row = e >> 5;
        const int d4 = (e & 31) << 2;
        float a0 = 0.f, a1 = 0.f, a2 = 0.f, a3 = 0.f;
#pragma unroll
        for (int ks = 0; ks < KSA; ++ks) {
            const short4 sp = *(const short4*)&Opart[((size_t)(bkvh * KSA + ks) * 64 + row) * 128 + d4];
            const float f = sf[ks][row];
            a0 = fmaf(f, bf2f(sp.x), a0);
            a1 = fmaf(f, bf2f(sp.y), a1);
            a2 = fmaf(f, bf2f(sp.z), a2);
            a3 = fmaf(f, bf2f(sp.w), a3);
        }
        const float iL = sinvL[row];
        a0 *= iL; a1 *= iL; a2 *= iL; a3 *= iL;
        const int hh = kvh * 4 + (row >> 4);
        const int tok = b * SEQ + (row & 15);
        const int col = hh * 128 + d4;
        short4 o;
        o.x = f2bf(a0); o.y = f2bf(a1); o.z = f2bf(a2); o.w = f2bf(a3);
        *(short4*)&aob[((size_t)(col >> 3) * 128 + tok) * 8 + (col & 7)] = o;
    }
}

// Sum the KSPLIT bf16 out-proj partials into f32 d_out.
__global__ __launch_bounds__(256) void sum_parts(const short* __restrict__ P,
                                                 float* __restrict__ out) {
    int i = blockIdx.x * 256 + threadIdx.x;     // over groups of 4 elems, 131072 total
    float a0 = 0.f, a1 = 0.f, a2 = 0.f, a3 = 0.f;
#pragma unroll
    for (int ks = 0; ks < KSPLIT; ++ks) {
        const short4 t = ((const short4*)(P + (size_t)ks * NTOK * 4096))[i];
        a0 += bf2f(t.x); a1 += bf2f(t.y); a2 += bf2f(t.z); a3 += bf2f(t.w);
    }
    ((float4*)out)[i] = make_float4(a0, a1, a2, a3);
}

extern "C" void kernel_launch(void* const* d_in, const int* in_sizes, int n_in,
                              void* d_out, int out_size, void* d_ws, size_t ws_size,
                              hipStream_t stream) {
    const float* x  = (const float*)d_in[0];
    const float* wq = (const float*)d_in[1];
    const float* wk = (const float*)d_in[2];
    const float* wv = (const float*)d_in[3];
    const float* wo = (const float*)d_in[4];
    const float* cs = (const float*)d_in[5];
    const float* sn = (const float*)d_in[6];
    const float* ck = (const float*)d_in[7];
    const float* cv = (const float*)d_in[8];
    const int* startp = (const int*)d_in[9];

    // ws layout. Pqb (16.78MB, KSPLIT=16) == Opart size exactly; Opart overlays
    // Pqb (Pq dead after combine_rot, Opart dead before out-proj writes Pqb).
    short* Pqb = (short*)d_ws;                                // KSPLIT*NTOK*4096
    short* Pkb = Pqb + (size_t)KSPLIT * NTOK * 4096;
    short* Pvb = Pkb + (size_t)KSPLIT * NTOK * 1024;
    short* Opart = Pqb;                                       // overlay
    float* qb   = (float*)(Pvb + (size_t)KSPLIT * NTOK * 1024);
    float* knb  = qb + (size_t)NTOK * 4096;
    float* vnb  = knb + (size_t)NTOK * 1024;
    short* xpre = (short*)(vnb + (size_t)NTOK * 1024);
    short* aob  = xpre + (size_t)NTOK * 4096;
    float* mpart = (float*)(aob + (size_t)NTOK * 4096);
    float* lpart = mpart + (size_t)64 * KSA * 64;
    // total ws ~31MB

    cvt_x<<<512, 256, 0, stream>>>(x, xpre);
    // QKV: (64 Q + 16 K + 16 V cbids) x KSPLIT=16 -> 1536 blocks = 24 waves/CU
    gemm_mfma<<<dim3(96, KSPLIT), 256, 0, stream>>>(xpre, wq, wk, wv, Pqb, Pkb, Pvb);
    combine_rot<<<1536, 256, 0, stream>>>(Pqb, Pkb, Pvb, qb, knb, vnb, cs, sn, startp);
    attn_fused<<<dim3(KSA, KVH, B_), 256, 0, stream>>>(qb, knb, vnb, ck, cv, Opart, mpart, lpart, startp);
    attn_merge<<<64, 256, 0, stream>>>(Opart, mpart, lpart, aob);
    // out-proj: 64 cbids x KSPLIT=16 -> 1024 blocks = 16 waves/CU (Q-branch, W=wo)
    gemm_mfma<<<dim3(64, KSPLIT), 256, 0, stream>>>(aob, wo, wo, wo, Pqb, Pqb, Pqb);
    sum_parts<<<512, 256, 0, stream>>>(Pqb, (float*)d_out);
}

// Round 8
// 111.812 us; speedup vs baseline: 1.1424x; 1.1105x over previous
//
#include <hip/hip_runtime.h>
#include <math.h>
#include <stdint.h>

#define D 4096
#define H 32
#define KVH 8
#define HD 128
#define B_ 8
#define SEQ 16
#define MAXLEN 2048
#define NTOK 128          // B_*SEQ
#define KSPLIT 8
#define KCH 512           // D / KSPLIT
#define BK 32
#define TSTEPS (KCH / BK) // 16
#define KSA 16            // attention key-split across blocks (merged by attn_merge)

typedef __attribute__((ext_vector_type(8))) short bh8;    // 8 bf16 (4 VGPRs)
typedef __attribute__((ext_vector_type(4))) float f32x4;  // MFMA C/D frag
typedef _Float16 f16x2 __attribute__((ext_vector_type(2)));
typedef _Float16 f16x8 __attribute__((ext_vector_type(8)));

static __device__ __forceinline__ int imin(int a, int b) { return a < b ? a : b; }

static __device__ __forceinline__ short f2bf(float x) {   // RNE f32 -> bf16 bits
    union { float f; uint32_t u; } v; v.f = x;
    uint32_t u = v.u;
    return (short)((u + 0x7fffu + ((u >> 16) & 1u)) >> 16);
}
static __device__ __forceinline__ float bf2f(short b) {
    union { uint32_t u; float f; } v; v.u = ((uint32_t)(uint16_t)b) << 16;
    return v.f;
}

static __device__ __forceinline__ float fexp2(float x) {
#if __has_builtin(__builtin_amdgcn_exp2f)
    return __builtin_amdgcn_exp2f(x);
#else
    return exp2f(x);
#endif
}

// x (128 x 4096 f32) -> bf16 in MFMA A-layout: xp[(kg*128 + row)*8 + j], k = kg*8+j.
__global__ __launch_bounds__(256) void cvt_x(const float* __restrict__ x, short* __restrict__ xp) {
    int i = blockIdx.x * 256 + threadIdx.x;   // 131072 float4s
    int row = i >> 10;
    int c4 = (i & 1023) << 2;                 // col, multiple of 4
    const float4 v = ((const float4*)x)[i];
    short4 o;
    o.x = f2bf(v.x); o.y = f2bf(v.y); o.z = f2bf(v.z); o.w = f2bf(v.w);
    *(short4*)&xp[((size_t)((c4 >> 3) * 128 + row)) * 8 + (c4 & 7)] = o;
}

// C_partial(bf16) = A(128 x K, bf16 pre-laid-out) @ W(K x ntot, f32 row-major).
//
// v9 = r2's v3 reg-direct GEMM with ONE change: __launch_bounds__(256, 2).
// r0-r7 post-mortem: every variant compiled to VGPR_Count=64 (compiler
// targeting max occupancy), which cannot hold the declared pipeline
// (acc 32 + wr0/wr1 32 + ar0/ar1 32 + addr) -> the compiler converts each
// W f32 to bf16 right after its load to free registers, forcing a waitcnt
// PER LOAD. Wave-lifetime arithmetic (Occ 30% x 52us / 6144 waves = 21us
// per wave = ~312 cyc/load, serialized; ~0.5 KB in flight per wave ->
// Little's law = 2.2 TB/s) matches the wall seen in all seven rounds,
// and explains structure-invariance. Fix: min-waves=2 -> VGPR cap 256;
// the honest ~130-reg pipeline fits, 20 loads (~8 KB) per wave stay in
// flight, 8 waves/CU x 8 KB = 64 KB/CU -> HBM-bound, not latency-bound.
__global__ __launch_bounds__(256, 2) void gemm_mfma(const short* __restrict__ xp,
                                                    const float* __restrict__ wq,
                                                    const float* __restrict__ wk,
                                                    const float* __restrict__ wv,
                                                    short* __restrict__ Pq,
                                                    short* __restrict__ Pk,
                                                    short* __restrict__ Pv) {
    const int cbid = blockIdx.x;
    const int ks = blockIdx.y;
    const float* W; short* P; int ntot; int cb;
    if (cbid < 64)      { W = wq; P = Pq; ntot = 4096; cb = cbid * 64; }
    else if (cbid < 80) { W = wk; P = Pk; ntot = 1024; cb = (cbid - 64) * 64; }
    else                { W = wv; P = Pv; ntot = 1024; cb = (cbid - 80) * 64; }
    const int tid = threadIdx.x;              // 0..255
    const int lane = tid & 63;
    const int w = tid >> 6;                   // wave 0..3
    const int wm = w >> 1, wn = w & 1;        // wave tile: rows wm*64, cols wn*32
    const int lrow = lane & 15, lkg = lane >> 4;
    const int k0 = ks * KCH;

    f32x4 acc[4][2];
#pragma unroll
    for (int fm = 0; fm < 4; ++fm)
#pragma unroll
        for (int fn = 0; fn < 2; ++fn) acc[fm][fn] = (f32x4){0.f, 0.f, 0.f, 0.f};

    // A: xp[(( (k0>>3) + t*4 + lkg )*128 + wm*64 + fm*16 + lrow)*8 + j]
    const short* abase = xp + ((size_t)((k0 >> 3) + lkg) * 128 + wm * 64 + lrow) * 8;
    // W: W[(k0 + t*32 + lkg*8 + j)*ntot + cb + wn*32 + fn*16 + lrow]
    const float* wbase = W + (size_t)(k0 + lkg * 8) * ntot + cb + wn * 32 + lrow;

    auto loadWf = [&](int t, float (&wr)[16]) {
        const float* p = wbase + (size_t)t * 32 * ntot;
#pragma unroll
        for (int j = 0; j < 8; ++j) {
            wr[j]     = p[0];    // fn = 0
            wr[8 + j] = p[16];   // fn = 1
            p += ntot;
        }
    };
    auto loadAf = [&](int t, bh8 (&ar)[4]) {
        const short* p = abase + (size_t)t * 4096;   // t*4 kgroups * 128 rows * 8
#pragma unroll
        for (int fm = 0; fm < 4; ++fm)
            ar[fm] = *(const bh8*)(p + fm * 128);
    };
    auto comp = [&](const bh8 (&ar)[4], const float (&wr)[16]) {
        bh8 bf0, bf1;
#pragma unroll
        for (int j = 0; j < 8; ++j) { bf0[j] = f2bf(wr[j]); bf1[j] = f2bf(wr[8 + j]); }
#pragma unroll
        for (int fm = 0; fm < 4; ++fm) {
            acc[fm][0] = __builtin_amdgcn_mfma_f32_16x16x32_bf16(ar[fm], bf0, acc[fm][0], 0, 0, 0);
            acc[fm][1] = __builtin_amdgcn_mfma_f32_16x16x32_bf16(ar[fm], bf1, acc[fm][1], 0, 0, 0);
        }
    };

    float wr0[16], wr1[16];
    bh8 ar0[4], ar1[4];
    loadWf(0, wr0); loadAf(0, ar0);
    for (int t = 0; t < TSTEPS; t += 2) {
        loadWf(t + 1, wr1); loadAf(t + 1, ar1);    // stage t+1 in flight under comp(t)
        comp(ar0, wr0);
        if (t + 2 < TSTEPS) { loadWf(t + 2, wr0); loadAf(t + 2, ar0); }
        comp(ar1, wr1);
    }

    short* pp = P + (size_t)ks * NTOK * ntot;
#pragma unroll
    for (int fm = 0; fm < 4; ++fm) {
        const int gr0 = wm * 64 + fm * 16 + lkg * 4;
#pragma unroll
        for (int fn = 0; fn < 2; ++fn) {
            const int gc = cb + wn * 32 + fn * 16 + lrow;
#pragma unroll
            for (int q = 0; q < 4; ++q)
                pp[(size_t)(gr0 + q) * ntot + gc] = f2bf(acc[fm][fn][q]);
        }
    }
}

// Sum K-split bf16 partials of Q/K/V; apply interleaved-pair rotary to q and k_new.
__global__ __launch_bounds__(256) void combine_rot(const short* __restrict__ Pq,
                                                   const short* __restrict__ Pk,
                                                   const short* __restrict__ Pv,
                                                   float* __restrict__ qb,
                                                   float* __restrict__ knb,
                                                   float* __restrict__ vnb,
                                                   const float* __restrict__ cosT,
                                                   const float* __restrict__ sinT,
                                                   const int* __restrict__ startp) {
    int gid = blockIdx.x * 256 + threadIdx.x;
    int tok = gid / 3072;
    int pr = gid % 3072;
    int col = pr * 2;
    int start = *startp;
    int pos = start + (tok & (SEQ - 1));
    float a = 0.f, b = 0.f;
    if (col < 4096) {
        const short* base = Pq + (size_t)tok * 4096 + col;
#pragma unroll
        for (int ks = 0; ks < KSPLIT; ++ks) {
            short2 t = *(const short2*)(base + (size_t)ks * NTOK * 4096);
            a += bf2f(t.x); b += bf2f(t.y);
        }
        int i = (col & 127) >> 1;
        float c = cosT[pos * 64 + i], s = sinT[pos * 64 + i];
        qb[(size_t)tok * 4096 + col]     = a * c - b * s;
        qb[(size_t)tok * 4096 + col + 1] = a * s + b * c;
    } else if (col < 5120) {
        int colr = col - 4096;
        const short* base = Pk + (size_t)tok * 1024 + colr;
#pragma unroll
        for (int ks = 0; ks < KSPLIT; ++ks) {
            short2 t = *(const short2*)(base + (size_t)ks * NTOK * 1024);
            a += bf2f(t.x); b += bf2f(t.y);
        }
        int i = (colr & 127) >> 1;
        float c = cosT[pos * 64 + i], s = sinT[pos * 64 + i];
        knb[(size_t)tok * 1024 + colr]     = a * c - b * s;
        knb[(size_t)tok * 1024 + colr + 1] = a * s + b * c;
    } else {
        int colr = col - 5120;
        const short* base = Pv + (size_t)tok * 1024 + colr;
#pragma unroll
        for (int ks = 0; ks < KSPLIT; ++ks) {
            short2 t = *(const short2*)(base + (size_t)ks * NTOK * 1024);
            a += bf2f(t.x); b += bf2f(t.y);
        }
        vnb[(size_t)tok * 1024 + colr]     = a;
        vnb[(size_t)tok * 1024 + colr + 1] = b;
    }
}

// MFMA attention partial pass. grid (ksb, kvh, b) = (16,8,8); block = 256 = 4 waves.
__global__ __launch_bounds__(256) void attn_fused(const float* __restrict__ qb,
                                                  const float* __restrict__ knb,
                                                  const float* __restrict__ vnb,
                                                  const float* __restrict__ ck,
                                                  const float* __restrict__ cv,
                                                  short* __restrict__ Opart,
                                                  float* __restrict__ mpart,
                                                  float* __restrict__ lpart,
                                                  const int* __restrict__ startp) {
    const int ksb = blockIdx.x;
    const int kvh = blockIdx.y;
    const int b   = blockIdx.z;
    const int start = *startp;
    const int klen = start + SEQ;
    const int chunk = (klen + KSA - 1) / KSA;        // 65
    const int bbeg = ksb * chunk;
    const int bend = imin(bbeg + chunk, klen);
    const int tiles = (chunk + 31) >> 5;             // 3, uniform across waves/blocks

    const int tid = threadIdx.x;
    const int w = tid >> 6, lane = tid & 63;
    const int c = lane & 15, g = lane >> 4;
    const int hh = kvh * 4 + w;

    __shared__ __align__(16) _Float16 Ksh[2][16][32][8];   // [buf][dg][slot][8] 16KB
    __shared__ __align__(16) _Float16 Vsh[2][4][128][8];   // [buf][kg][d][key&7] 16KB

    const float scl2 = 0.08838834764831843f * 1.4426950408889634f;  // 1/sqrt(128)*log2e

    f16x8 qfr[4];
    {
        const float* qp = qb + (size_t)(b * SEQ + c) * 4096 + hh * 128 + 8 * g;
#pragma unroll
        for (int h = 0; h < 4; ++h) {
            float4 a = *(const float4*)(qp + 32 * h);
            float4 b2 = *(const float4*)(qp + 32 * h + 4);
            qfr[h][0] = (_Float16)(a.x * scl2);  qfr[h][1] = (_Float16)(a.y * scl2);
            qfr[h][2] = (_Float16)(a.z * scl2);  qfr[h][3] = (_Float16)(a.w * scl2);
            qfr[h][4] = (_Float16)(b2.x * scl2); qfr[h][5] = (_Float16)(b2.y * scl2);
            qfr[h][6] = (_Float16)(b2.z * scl2); qfr[h][7] = (_Float16)(b2.w * scl2);
        }
    }

    f32x4 acc_o[8];
#pragma unroll
    for (int dm = 0; dm < 8; ++dm) acc_o[dm] = (f32x4){0.f, 0.f, 0.f, 0.f};
    float mrun = -INFINITY, lrun = 0.f;

    const int s_   = tid & 31;
    const int dgA  = tid >> 5;             // 0..7
    const int koffK = 8 * ((s_ >> 2) & 3) + 4 * (s_ >> 4) + (s_ & 3);
    const int kg0 = tid >> 6, d0 = (tid & 63) * 2;

    float4 kr0, kr1, kr2, kr3;
    float2 vrw[8];
    auto gloadRaw = [&](int t) {
        const int kp = bbeg + t * 32 + koffK;
        kr0 = (float4){0.f,0.f,0.f,0.f}; kr1 = kr0; kr2 = kr0; kr3 = kr0;
        if (kp < bend) {
            const float* kr = (kp < start)
                ? ck + ((size_t)((b * MAXLEN + kp) * KVH + kvh)) * HD
                : knb + (size_t)(b * SEQ + kp - start) * 1024 + kvh * HD;
            kr0 = *(const float4*)(kr + dgA * 8);
            kr1 = *(const float4*)(kr + dgA * 8 + 4);
            kr2 = *(const float4*)(kr + dgA * 8 + 64);
            kr3 = *(const float4*)(kr + dgA * 8 + 68);
        }
#pragma unroll
        for (int j = 0; j < 8; ++j) {
            const int kpv = bbeg + t * 32 + kg0 * 8 + j;
            vrw[j] = (float2){0.f, 0.f};
            if (kpv < bend) {
                const float* vrp = (kpv < start)
                    ? cv + ((size_t)((b * MAXLEN + kpv) * KVH + kvh)) * HD + d0
                    : vnb + (size_t)(b * SEQ + kpv - start) * 1024 + kvh * HD + d0;
                vrw[j] = *(const float2*)vrp;
            }
        }
    };
    auto cvtStore = [&](int bf) {
        f16x8 ka, kb;
        ka[0]=(_Float16)kr0.x; ka[1]=(_Float16)kr0.y; ka[2]=(_Float16)kr0.z; ka[3]=(_Float16)kr0.w;
        ka[4]=(_Float16)kr1.x; ka[5]=(_Float16)kr1.y; ka[6]=(_Float16)kr1.z; ka[7]=(_Float16)kr1.w;
        kb[0]=(_Float16)kr2.x; kb[1]=(_Float16)kr2.y; kb[2]=(_Float16)kr2.z; kb[3]=(_Float16)kr2.w;
        kb[4]=(_Float16)kr3.x; kb[5]=(_Float16)kr3.y; kb[6]=(_Float16)kr3.z; kb[7]=(_Float16)kr3.w;
        *(f16x8*)&Ksh[bf][dgA][s_][0] = ka;
        *(f16x8*)&Ksh[bf][dgA + 8][s_][0] = kb;
        f16x8 w0, w1;
#pragma unroll
        for (int j = 0; j < 8; ++j) { w0[j] = (_Float16)vrw[j].x; w1[j] = (_Float16)vrw[j].y; }
        *(f16x8*)&Vsh[bf][kg0][d0][0] = w0;
        *(f16x8*)&Vsh[bf][kg0][d0 + 1][0] = w1;
    };

    gloadRaw(0);
    cvtStore(0);
    __syncthreads();

    int buf = 0;
    for (int t = 0; t < tiles; ++t) {
        if (t + 1 < tiles) gloadRaw(t + 1);
        const int nk = imin(32, bend - (bbeg + t * 32));

        f32x4 acc_s[2];
        acc_s[0] = (f32x4){0.f, 0.f, 0.f, 0.f};
        acc_s[1] = (f32x4){0.f, 0.f, 0.f, 0.f};
#pragma unroll
        for (int h = 0; h < 4; ++h) {
#pragma unroll
            for (int m = 0; m < 2; ++m) {
                const f16x8 afr = *(const f16x8*)&Ksh[buf][h * 4 + g][m * 16 + c][0];
                acc_s[m] = __builtin_amdgcn_mfma_f32_16x16x32_f16(afr, qfr[h], acc_s[m], 0, 0, 0);
            }
        }
        float s8[8];
#pragma unroll
        for (int m = 0; m < 2; ++m)
#pragma unroll
            for (int q = 0; q < 4; ++q) s8[m * 4 + q] = acc_s[m][q];
        if (nk < 32) {
#pragma unroll
            for (int jj = 0; jj < 8; ++jj)
                if (8 * g + jj >= nk) s8[jj] = -1e30f;
        }
        float tmax = s8[0];
#pragma unroll
        for (int jj = 1; jj < 8; ++jj) tmax = fmaxf(tmax, s8[jj]);
        tmax = fmaxf(tmax, __shfl_xor(tmax, 16));
        tmax = fmaxf(tmax, __shfl_xor(tmax, 32));
        if (__any(tmax > mrun + 11.5f)) {
            const float mn = fmaxf(mrun, tmax);
            const float fac = fexp2(mrun - mn);
            lrun *= fac;
#pragma unroll
            for (int dm = 0; dm < 8; ++dm) {
                acc_o[dm][0] *= fac; acc_o[dm][1] *= fac;
                acc_o[dm][2] *= fac; acc_o[dm][3] *= fac;
            }
            mrun = mn;
        }
        float pe[8];
#pragma unroll
        for (int jj = 0; jj < 8; ++jj) pe[jj] = fexp2(s8[jj] - mrun);
#pragma unroll
        for (int jj = 0; jj < 8; ++jj) lrun += pe[jj];
        f16x8 bp;
#pragma unroll
        for (int jj = 0; jj < 8; ++jj) bp[jj] = (_Float16)pe[jj];

#pragma unroll
        for (int dm = 0; dm < 8; ++dm) {
            const f16x8 av = *(const f16x8*)&Vsh[buf][g][dm * 16 + c][0];
            acc_o[dm] = __builtin_amdgcn_mfma_f32_16x16x32_f16(av, bp, acc_o[dm], 0, 0, 0);
        }

        if (t + 1 < tiles) cvtStore(buf ^ 1);
        __syncthreads();
        buf ^= 1;
    }

    lrun += __shfl_xor(lrun, 16);
    lrun += __shfl_xor(lrun, 32);

    const int base = ((b * KVH + kvh) * KSA + ksb) * 64;
    const int row = w * 16 + c;
#pragma unroll
    for (int dm = 0; dm < 8; ++dm) {
        short4 o4;
        o4.x = f2bf(acc_o[dm][0]); o4.y = f2bf(acc_o[dm][1]);
        o4.z = f2bf(acc_o[dm][2]); o4.w = f2bf(acc_o[dm][3]);
        *(short4*)&Opart[(size_t)(base + row) * 128 + dm * 16 + g * 4] = o4;
    }
    if (g == 0) { mpart[base + row] = mrun; lpart[base + row] = lrun; }
}

// Merge KSA partials -> aob (bf16, out-proj A-layout). m/l are exp2-domain.
__global__ __launch_bounds__(256) void attn_merge(const short* __restrict__ Opart,
                                                  const float* __restrict__ mpart,
                                                  const float* __restrict__ lpart,
                                                  short* __restrict__ aob) {
    const int bkvh = blockIdx.x;
    const int tid = threadIdx.x;
    __shared__ float sf[KSA][64];
    __shared__ float sinvL[64];
    if (tid < 64) {
        const int row = tid;
        float M = -INFINITY;
#pragma unroll
        for (int ks = 0; ks < KSA; ++ks)
            M = fmaxf(M, mpart[(size_t)(bkvh * KSA + ks) * 64 + row]);
        float L = 0.f;
#pragma unroll
        for (int ks = 0; ks < KSA; ++ks) {
            float f = exp2f(mpart[(size_t)(bkvh * KSA + ks) * 64 + row] - M);
            sf[ks][row] = f;
            L += f * lpart[(size_t)(bkvh * KSA + ks) * 64 + row];
        }
        sinvL[row] = 1.f / L;
    }
    __syncthreads();
    const int b = bkvh >> 3, kvh = bkvh & 7;
    for (int e = tid; e < 2048; e += 256) {
        const int row = e >> 5;
        const int d4 = (e & 31) << 2;
        float a0 = 0.f, a1 = 0.f, a2 = 0.f, a3 = 0.f;
#pragma unroll
        for (int ks = 0; ks < KSA; ++ks) {
            const short4 sp = *(const short4*)&Opart[((size_t)(bkvh * KSA + ks) * 64 + row) * 128 + d4];
            const float f = sf[ks][row];
            a0 = fmaf(f, bf2f(sp.x), a0);
            a1 = fmaf(f, bf2f(sp.y), a1);
            a2 = fmaf(f, bf2f(sp.z), a2);
            a3 = fmaf(f, bf2f(sp.w), a3);
        }
        const float iL = sinvL[row];
        a0 *= iL; a1 *= iL; a2 *= iL; a3 *= iL;
        const int hh = kvh * 4 + (row >> 4);
        const int tok = b * SEQ + (row & 15);
        const int col = hh * 128 + d4;
        short4 o;
        o.x = f2bf(a0); o.y = f2bf(a1); o.z = f2bf(a2); o.w = f2bf(a3);
        *(short4*)&aob[((size_t)(col >> 3) * 128 + tok) * 8 + (col & 7)] = o;
    }
}

// Sum the KSPLIT bf16 out-proj partials into f32 d_out.
__global__ __launch_bounds__(256) void sum_parts(const short* __restrict__ P,
                                                 float* __restrict__ out) {
    int i = blockIdx.x * 256 + threadIdx.x;     // over groups of 4 elems, 131072 total
    float a0 = 0.f, a1 = 0.f, a2 = 0.f, a3 = 0.f;
#pragma unroll
    for (int ks = 0; ks < KSPLIT; ++ks) {
        const short4 t = ((const short4*)(P + (size_t)ks * NTOK * 4096))[i];
        a0 += bf2f(t.x); a1 += bf2f(t.y); a2 += bf2f(t.z); a3 += bf2f(t.w);
    }
    ((float4*)out)[i] = make_float4(a0, a1, a2, a3);
}

extern "C" void kernel_launch(void* const* d_in, const int* in_sizes, int n_in,
                              void* d_out, int out_size, void* d_ws, size_t ws_size,
                              hipStream_t stream) {
    const float* x  = (const float*)d_in[0];
    const float* wq = (const float*)d_in[1];
    const float* wk = (const float*)d_in[2];
    const float* wv = (const float*)d_in[3];
    const float* wo = (const float*)d_in[4];
    const float* cs = (const float*)d_in[5];
    const float* sn = (const float*)d_in[6];
    const float* ck = (const float*)d_in[7];
    const float* cv = (const float*)d_in[8];
    const int* startp = (const int*)d_in[9];

    // ws layout (bf16 partials). Opart (16.8MB) overlays Pqb+Pkb+Pvb (12.6MB) plus
    // 4.2MB of pad; all live buffers start after Opart's full extent.
    short* Opart = (short*)d_ws;                              // 64*16*64*128 shorts
    short* Pqb = Opart;                                       // dead by attn time
    short* Pkb = Pqb + (size_t)KSPLIT * NTOK * 4096;
    short* Pvb = Pkb + (size_t)KSPLIT * NTOK * 1024;
    float* qb   = (float*)(Opart + (size_t)64 * KSA * 64 * 128);  // after 16.8MB
    float* knb  = qb + (size_t)NTOK * 4096;
    float* vnb  = knb + (size_t)NTOK * 1024;
    short* xpre = (short*)(vnb + (size_t)NTOK * 1024);
    short* aob  = xpre + (size_t)NTOK * 4096;
    float* mpart = (float*)(aob + (size_t)NTOK * 4096);
    float* lpart = mpart + (size_t)64 * KSA * 64;
    // total ws ~22.3MB

    cvt_x<<<512, 256, 0, stream>>>(x, xpre);
    // QKV: 64 Q col-blocks (NT=64) + 16 K + 16 V, x KSPLIT=8
    gemm_mfma<<<dim3(96, KSPLIT), 256, 0, stream>>>(xpre, wq, wk, wv, Pqb, Pkb, Pvb);
    combine_rot<<<1536, 256, 0, stream>>>(Pqb, Pkb, Pvb, qb, knb, vnb, cs, sn, startp);
    attn_fused<<<dim3(KSA, KVH, B_), 256, 0, stream>>>(qb, knb, vnb, ck, cv, Opart, mpart, lpart, startp);
    attn_merge<<<64, 256, 0, stream>>>(Opart, mpart, lpart, aob);
    // out-proj: 64 col-blocks (NT=64) x KSPLIT=8, all take the Q branch (W=wo)
    gemm_mfma<<<dim3(64, KSPLIT), 256, 0, stream>>>(aob, wo, wo, wo, Pqb, Pqb, Pqb);
    sum_parts<<<512, 256, 0, stream>>>(Pqb, (float*)d_out);
}

// Round 9
// 102.599 us; speedup vs baseline: 1.2449x; 1.0898x over previous
//
#include <hip/hip_runtime.h>
#include <math.h>
#include <stdint.h>

#define D 4096
#define H 32
#define KVH 8
#define HD 128
#define B_ 8
#define SEQ 16
#define MAXLEN 2048
#define NTOK 128          // B_*SEQ
#define KSPLIT 8
#define KCH 512           // D / KSPLIT
#define BK 32
#define TSTEPS (KCH / BK) // 16
#define KSA 16            // attention key-split across blocks (merged by attn_merge)

typedef __attribute__((ext_vector_type(8))) short bh8;    // 8 bf16 (4 VGPRs)
typedef __attribute__((ext_vector_type(4))) float f32x4;  // MFMA C/D frag
typedef _Float16 f16x2 __attribute__((ext_vector_type(2)));
typedef _Float16 f16x8 __attribute__((ext_vector_type(8)));

static __device__ __forceinline__ int imin(int a, int b) { return a < b ? a : b; }

static __device__ __forceinline__ short f2bf(float x) {   // RNE f32 -> bf16 bits
    union { float f; uint32_t u; } v; v.f = x;
    uint32_t u = v.u;
    return (short)((u + 0x7fffu + ((u >> 16) & 1u)) >> 16);
}
static __device__ __forceinline__ float bf2f(short b) {
    union { uint32_t u; float f; } v; v.u = ((uint32_t)(uint16_t)b) << 16;
    return v.f;
}

static __device__ __forceinline__ float fexp2(float x) {
#if __has_builtin(__builtin_amdgcn_exp2f)
    return __builtin_amdgcn_exp2f(x);
#else
    return exp2f(x);
#endif
}

static __device__ __forceinline__ void gll16(const void* g, void* l) {
    __builtin_amdgcn_global_load_lds((const __attribute__((address_space(1))) uint32_t*)g,
                                     (__attribute__((address_space(3))) uint32_t*)l, 16, 0, 0);
}

// x (128 x 4096 f32) -> bf16 in MFMA A-layout: xp[(kg*128 + row)*8 + j], k = kg*8+j.
__global__ __launch_bounds__(256) void cvt_x(const float* __restrict__ x, short* __restrict__ xp) {
    int i = blockIdx.x * 256 + threadIdx.x;   // 131072 float4s
    int row = i >> 10;
    int c4 = (i & 1023) << 2;                 // col, multiple of 4
    const float4 v = ((const float4*)x)[i];
    short4 o;
    o.x = f2bf(v.x); o.y = f2bf(v.y); o.z = f2bf(v.z); o.w = f2bf(v.w);
    *(short4*)&xp[((size_t)((c4 >> 3) * 128 + row)) * 8 + (c4 & 7)] = o;
}

// C_partial(bf16) = A(128 x K, bf16 pre-laid-out) @ W(K x ntot, f32 row-major).
//
// v10: gll + COUNTED vmcnt + RAW s_barrier (T3/T4) — the one combination
// never tried. r8 proved register pipelining is compiler-refused (cap raised
// to 256, VGPR stayed 64: hipcc converts-early and serializes the W stream
// regardless of launch_bounds). global_load_lds keeps loads in flight with
// NO register footprint and NO compiler discretion: queue depth = vmcnt.
//  - ring-3 LDS buffers, 16KB each: A slab 8KB (xp is k-group-major so the
//    step's A tile is 8KB CONTIGUOUS) + W tile 8KB (32 rows x 64 cols f32).
//  - stage depth 2 ahead: 4 glls/thread/stage; in-loop wait = vmcnt(4)
//    (next-needed buffer's glls done, one stage stays in flight across the
//    raw s_barrier — never vmcnt(0) until the tail).
//  - ring-3 + depth-2 => a buffer is rewritten one full barrier AFTER its
//    last reader finished (no race).
//  - 48KB LDS -> 3 blocks/CU = 12 waves; 8KB in flight per wave = 96KB/CU
//    (vs ~1KB/wave in v1-v9) -> Little's-law capacity >> HBM.
__global__ __launch_bounds__(256, 2) void gemm_mfma(const short* __restrict__ xp,
                                                    const float* __restrict__ wq,
                                                    const float* __restrict__ wk,
                                                    const float* __restrict__ wv,
                                                    short* __restrict__ Pq,
                                                    short* __restrict__ Pk,
                                                    short* __restrict__ Pv) {
    const int cbid = blockIdx.x;
    const int ks = blockIdx.y;
    const float* W; short* P; int ntot; int cb;
    if (cbid < 64)      { W = wq; P = Pq; ntot = 4096; cb = cbid * 64; }
    else if (cbid < 80) { W = wk; P = Pk; ntot = 1024; cb = (cbid - 64) * 64; }
    else                { W = wv; P = Pv; ntot = 1024; cb = (cbid - 80) * 64; }
    const int tid = threadIdx.x;              // 0..255
    const int lane = tid & 63;
    const int w = tid >> 6;                   // wave 0..3
    const int wm = w >> 1, wn = w & 1;        // wave tile: rows wm*64, cols wn*32
    const int lrow = lane & 15, lkg = lane >> 4;
    const int k0 = ks * KCH;

    __shared__ __align__(16) char smem[3][16384];   // [buf][ A 8KB | W 8KB ]

    f32x4 acc[4][2];
#pragma unroll
    for (int fm = 0; fm < 4; ++fm)
#pragma unroll
        for (int fn = 0; fn < 2; ++fn) acc[fm][fn] = (f32x4){0.f, 0.f, 0.f, 0.f};

    // A slab for step t: xp shorts [((k0>>3)+t*4)*1024 .. +4096) — contiguous 8KB.
    const short* aslab0 = xp + (size_t)(k0 >> 3) * 1024;
    const int wr_ = tid >> 4;                 // 0..15 (W row within half-tile)
    const int wc4 = (tid & 15) * 4;           // W col group

    auto stage = [&](int t, int bf) {
        char* Ab = smem[bf];
        char* Wb = smem[bf] + 8192;
        const short* asrc = aslab0 + (size_t)t * 4096 + tid * 8;
        gll16(asrc,        Ab + tid * 16);
        gll16(asrc + 2048, Ab + 4096 + tid * 16);
        const float* wsrc = W + (size_t)(k0 + t * 32 + wr_) * ntot + cb + wc4;
        gll16(wsrc,                     Wb + tid * 16);          // rows 0..15
        gll16(wsrc + (size_t)16 * ntot, Wb + 4096 + tid * 16);   // rows 16..31
    };

    auto compute = [&](int bf) {
        const short* Ash = (const short*)smem[bf];
        const float* Wsh = (const float*)(smem[bf] + 8192);      // [row32][col64]
        bh8 afr[4];
#pragma unroll
        for (int fm = 0; fm < 4; ++fm)
            afr[fm] = *(const bh8*)&Ash[(lkg * 128 + wm * 64 + fm * 16 + lrow) * 8];
#pragma unroll
        for (int fn = 0; fn < 2; ++fn) {
            const int col = wn * 32 + fn * 16 + lrow;
            bh8 bfr;
#pragma unroll
            for (int j = 0; j < 8; ++j)
                bfr[j] = f2bf(Wsh[(lkg * 8 + j) * 64 + col]);
#pragma unroll
            for (int fm = 0; fm < 4; ++fm)
                acc[fm][fn] = __builtin_amdgcn_mfma_f32_16x16x32_bf16(afr[fm], bfr, acc[fm][fn], 0, 0, 0);
        }
    };

    stage(0, 0);
    stage(1, 1);
    asm volatile("s_waitcnt vmcnt(4)" ::: "memory");   // stage(0) done; stage(1) in flight
    __builtin_amdgcn_s_barrier();

    for (int t = 0; t < TSTEPS; ++t) {
        compute(t % 3);
        if (t + 2 < TSTEPS) stage(t + 2, (t + 2) % 3);
        if (t + 1 < TSTEPS) {
            if (t + 2 < TSTEPS) asm volatile("s_waitcnt vmcnt(4)" ::: "memory");
            else                asm volatile("s_waitcnt vmcnt(0)" ::: "memory");
            __builtin_amdgcn_s_barrier();              // raw: in-flight glls NOT drained
        }
    }

    short* pp = P + (size_t)ks * NTOK * ntot;
#pragma unroll
    for (int fm = 0; fm < 4; ++fm) {
        const int gr0 = wm * 64 + fm * 16 + lkg * 4;
#pragma unroll
        for (int fn = 0; fn < 2; ++fn) {
            const int gc = cb + wn * 32 + fn * 16 + lrow;
#pragma unroll
            for (int q = 0; q < 4; ++q)
                pp[(size_t)(gr0 + q) * ntot + gc] = f2bf(acc[fm][fn][q]);
        }
    }
}

// Sum K-split bf16 partials of Q/K/V; apply interleaved-pair rotary to q and k_new.
__global__ __launch_bounds__(256) void combine_rot(const short* __restrict__ Pq,
                                                   const short* __restrict__ Pk,
                                                   const short* __restrict__ Pv,
                                                   float* __restrict__ qb,
                                                   float* __restrict__ knb,
                                                   float* __restrict__ vnb,
                                                   const float* __restrict__ cosT,
                                                   const float* __restrict__ sinT,
                                                   const int* __restrict__ startp) {
    int gid = blockIdx.x * 256 + threadIdx.x;
    int tok = gid / 3072;
    int pr = gid % 3072;
    int col = pr * 2;
    int start = *startp;
    int pos = start + (tok & (SEQ - 1));
    float a = 0.f, b = 0.f;
    if (col < 4096) {
        const short* base = Pq + (size_t)tok * 4096 + col;
#pragma unroll
        for (int ks = 0; ks < KSPLIT; ++ks) {
            short2 t = *(const short2*)(base + (size_t)ks * NTOK * 4096);
            a += bf2f(t.x); b += bf2f(t.y);
        }
        int i = (col & 127) >> 1;
        float c = cosT[pos * 64 + i], s = sinT[pos * 64 + i];
        qb[(size_t)tok * 4096 + col]     = a * c - b * s;
        qb[(size_t)tok * 4096 + col + 1] = a * s + b * c;
    } else if (col < 5120) {
        int colr = col - 4096;
        const short* base = Pk + (size_t)tok * 1024 + colr;
#pragma unroll
        for (int ks = 0; ks < KSPLIT; ++ks) {
            short2 t = *(const short2*)(base + (size_t)ks * NTOK * 1024);
            a += bf2f(t.x); b += bf2f(t.y);
        }
        int i = (colr & 127) >> 1;
        float c = cosT[pos * 64 + i], s = sinT[pos * 64 + i];
        knb[(size_t)tok * 1024 + colr]     = a * c - b * s;
        knb[(size_t)tok * 1024 + colr + 1] = a * s + b * c;
    } else {
        int colr = col - 5120;
        const short* base = Pv + (size_t)tok * 1024 + colr;
#pragma unroll
        for (int ks = 0; ks < KSPLIT; ++ks) {
            short2 t = *(const short2*)(base + (size_t)ks * NTOK * 1024);
            a += bf2f(t.x); b += bf2f(t.y);
        }
        vnb[(size_t)tok * 1024 + colr]     = a;
        vnb[(size_t)tok * 1024 + colr + 1] = b;
    }
}

// MFMA attention partial pass. grid (ksb, kvh, b) = (16,8,8); block = 256 = 4 waves.
__global__ __launch_bounds__(256) void attn_fused(const float* __restrict__ qb,
                                                  const float* __restrict__ knb,
                                                  const float* __restrict__ vnb,
                                                  const float* __restrict__ ck,
                                                  const float* __restrict__ cv,
                                                  short* __restrict__ Opart,
                                                  float* __restrict__ mpart,
                                                  float* __restrict__ lpart,
                                                  const int* __restrict__ startp) {
    const int ksb = blockIdx.x;
    const int kvh = blockIdx.y;
    const int b   = blockIdx.z;
    const int start = *startp;
    const int klen = start + SEQ;
    const int chunk = (klen + KSA - 1) / KSA;        // 65
    const int bbeg = ksb * chunk;
    const int bend = imin(bbeg + chunk, klen);
    const int tiles = (chunk + 31) >> 5;             // 3, uniform across waves/blocks

    const int tid = threadIdx.x;
    const int w = tid >> 6, lane = tid & 63;
    const int c = lane & 15, g = lane >> 4;
    const int hh = kvh * 4 + w;

    __shared__ __align__(16) _Float16 Ksh[2][16][32][8];   // [buf][dg][slot][8] 16KB
    __shared__ __align__(16) _Float16 Vsh[2][4][128][8];   // [buf][kg][d][key&7] 16KB

    const float scl2 = 0.08838834764831843f * 1.4426950408889634f;  // 1/sqrt(128)*log2e

    f16x8 qfr[4];
    {
        const float* qp = qb + (size_t)(b * SEQ + c) * 4096 + hh * 128 + 8 * g;
#pragma unroll
        for (int h = 0; h < 4; ++h) {
            float4 a = *(const float4*)(qp + 32 * h);
            float4 b2 = *(const float4*)(qp + 32 * h + 4);
            qfr[h][0] = (_Float16)(a.x * scl2);  qfr[h][1] = (_Float16)(a.y * scl2);
            qfr[h][2] = (_Float16)(a.z * scl2);  qfr[h][3] = (_Float16)(a.w * scl2);
            qfr[h][4] = (_Float16)(b2.x * scl2); qfr[h][5] = (_Float16)(b2.y * scl2);
            qfr[h][6] = (_Float16)(b2.z * scl2); qfr[h][7] = (_Float16)(b2.w * scl2);
        }
    }

    f32x4 acc_o[8];
#pragma unroll
    for (int dm = 0; dm < 8; ++dm) acc_o[dm] = (f32x4){0.f, 0.f, 0.f, 0.f};
    float mrun = -INFINITY, lrun = 0.f;

    const int s_   = tid & 31;
    const int dgA  = tid >> 5;             // 0..7
    const int koffK = 8 * ((s_ >> 2) & 3) + 4 * (s_ >> 4) + (s_ & 3);
    const int kg0 = tid >> 6, d0 = (tid & 63) * 2;

    float4 kr0, kr1, kr2, kr3;
    float2 vrw[8];
    auto gloadRaw = [&](int t) {
        const int kp = bbeg + t * 32 + koffK;
        kr0 = (float4){0.f,0.f,0.f,0.f}; kr1 = kr0; kr2 = kr0; kr3 = kr0;
        if (kp < bend) {
            const float* kr = (kp < start)
                ? ck + ((size_t)((b * MAXLEN + kp) * KVH + kvh)) * HD
                : knb + (size_t)(b * SEQ + kp - start) * 1024 + kvh * HD;
            kr0 = *(const float4*)(kr + dgA * 8);
            kr1 = *(const float4*)(kr + dgA * 8 + 4);
            kr2 = *(const float4*)(kr + dgA * 8 + 64);
            kr3 = *(const float4*)(kr + dgA * 8 + 68);
        }
#pragma unroll
        for (int j = 0; j < 8; ++j) {
            const int kpv = bbeg + t * 32 + kg0 * 8 + j;
            vrw[j] = (float2){0.f, 0.f};
            if (kpv < bend) {
                const float* vrp = (kpv < start)
                    ? cv + ((size_t)((b * MAXLEN + kpv) * KVH + kvh)) * HD + d0
                    : vnb + (size_t)(b * SEQ + kpv - start) * 1024 + kvh * HD + d0;
                vrw[j] = *(const float2*)vrp;
            }
        }
    };
    auto cvtStore = [&](int bf) {
        f16x8 ka, kb;
        ka[0]=(_Float16)kr0.x; ka[1]=(_Float16)kr0.y; ka[2]=(_Float16)kr0.z; ka[3]=(_Float16)kr0.w;
        ka[4]=(_Float16)kr1.x; ka[5]=(_Float16)kr1.y; ka[6]=(_Float16)kr1.z; ka[7]=(_Float16)kr1.w;
        kb[0]=(_Float16)kr2.x; kb[1]=(_Float16)kr2.y; kb[2]=(_Float16)kr2.z; kb[3]=(_Float16)kr2.w;
        kb[4]=(_Float16)kr3.x; kb[5]=(_Float16)kr3.y; kb[6]=(_Float16)kr3.z; kb[7]=(_Float16)kr3.w;
        *(f16x8*)&Ksh[bf][dgA][s_][0] = ka;
        *(f16x8*)&Ksh[bf][dgA + 8][s_][0] = kb;
        f16x8 w0, w1;
#pragma unroll
        for (int j = 0; j < 8; ++j) { w0[j] = (_Float16)vrw[j].x; w1[j] = (_Float16)vrw[j].y; }
        *(f16x8*)&Vsh[bf][kg0][d0][0] = w0;
        *(f16x8*)&Vsh[bf][kg0][d0 + 1][0] = w1;
    };

    gloadRaw(0);
    cvtStore(0);
    __syncthreads();

    int buf = 0;
    for (int t = 0; t < tiles; ++t) {
        if (t + 1 < tiles) gloadRaw(t + 1);
        const int nk = imin(32, bend - (bbeg + t * 32));

        f32x4 acc_s[2];
        acc_s[0] = (f32x4){0.f, 0.f, 0.f, 0.f};
        acc_s[1] = (f32x4){0.f, 0.f, 0.f, 0.f};
#pragma unroll
        for (int h = 0; h < 4; ++h) {
#pragma unroll
            for (int m = 0; m < 2; ++m) {
                const f16x8 afr = *(const f16x8*)&Ksh[buf][h * 4 + g][m * 16 + c][0];
                acc_s[m] = __builtin_amdgcn_mfma_f32_16x16x32_f16(afr, qfr[h], acc_s[m], 0, 0, 0);
            }
        }
        float s8[8];
#pragma unroll
        for (int m = 0; m < 2; ++m)
#pragma unroll
            for (int q = 0; q < 4; ++q) s8[m * 4 + q] = acc_s[m][q];
        if (nk < 32) {
#pragma unroll
            for (int jj = 0; jj < 8; ++jj)
                if (8 * g + jj >= nk) s8[jj] = -1e30f;
        }
        float tmax = s8[0];
#pragma unroll
        for (int jj = 1; jj < 8; ++jj) tmax = fmaxf(tmax, s8[jj]);
        tmax = fmaxf(tmax, __shfl_xor(tmax, 16));
        tmax = fmaxf(tmax, __shfl_xor(tmax, 32));
        if (__any(tmax > mrun + 11.5f)) {
            const float mn = fmaxf(mrun, tmax);
            const float fac = fexp2(mrun - mn);
            lrun *= fac;
#pragma unroll
            for (int dm = 0; dm < 8; ++dm) {
                acc_o[dm][0] *= fac; acc_o[dm][1] *= fac;
                acc_o[dm][2] *= fac; acc_o[dm][3] *= fac;
            }
            mrun = mn;
        }
        float pe[8];
#pragma unroll
        for (int jj = 0; jj < 8; ++jj) pe[jj] = fexp2(s8[jj] - mrun);
#pragma unroll
        for (int jj = 0; jj < 8; ++jj) lrun += pe[jj];
        f16x8 bp;
#pragma unroll
        for (int jj = 0; jj < 8; ++jj) bp[jj] = (_Float16)pe[jj];

#pragma unroll
        for (int dm = 0; dm < 8; ++dm) {
            const f16x8 av = *(const f16x8*)&Vsh[buf][g][dm * 16 + c][0];
            acc_o[dm] = __builtin_amdgcn_mfma_f32_16x16x32_f16(av, bp, acc_o[dm], 0, 0, 0);
        }

        if (t + 1 < tiles) cvtStore(buf ^ 1);
        __syncthreads();
        buf ^= 1;
    }

    lrun += __shfl_xor(lrun, 16);
    lrun += __shfl_xor(lrun, 32);

    const int base = ((b * KVH + kvh) * KSA + ksb) * 64;
    const int row = w * 16 + c;
#pragma unroll
    for (int dm = 0; dm < 8; ++dm) {
        short4 o4;
        o4.x = f2bf(acc_o[dm][0]); o4.y = f2bf(acc_o[dm][1]);
        o4.z = f2bf(acc_o[dm][2]); o4.w = f2bf(acc_o[dm][3]);
        *(short4*)&Opart[(size_t)(base + row) * 128 + dm * 16 + g * 4] = o4;
    }
    if (g == 0) { mpart[base + row] = mrun; lpart[base + row] = lrun; }
}

// Merge KSA partials -> aob (bf16, out-proj A-layout). m/l are exp2-domain.
__global__ __launch_bounds__(256) void attn_merge(const short* __restrict__ Opart,
                                                  const float* __restrict__ mpart,
                                                  const float* __restrict__ lpart,
                                                  short* __restrict__ aob) {
    const int bkvh = blockIdx.x;
    const int tid = threadIdx.x;
    __shared__ float sf[KSA][64];
    __shared__ float sinvL[64];
    if (tid < 64) {
        const int row = tid;
        float M = -INFINITY;
#pragma unroll
        for (int ks = 0; ks < KSA; ++ks)
            M = fmaxf(M, mpart[(size_t)(bkvh * KSA + ks) * 64 + row]);
        float L = 0.f;
#pragma unroll
        for (int ks = 0; ks < KSA; ++ks) {
            float f = exp2f(mpart[(size_t)(bkvh * KSA + ks) * 64 + row] - M);
            sf[ks][row] = f;
            L += f * lpart[(size_t)(bkvh * KSA + ks) * 64 + row];
        }
        sinvL[row] = 1.f / L;
    }
    __syncthreads();
    const int b = bkvh >> 3, kvh = bkvh & 7;
    for (int e = tid; e < 2048; e += 256) {
        const int row = e >> 5;
        const int d4 = (e & 31) << 2;
        float a0 = 0.f, a1 = 0.f, a2 = 0.f, a3 = 0.f;
#pragma unroll
        for (int ks = 0; ks < KSA; ++ks) {
            const short4 sp = *(const short4*)&Opart[((size_t)(bkvh * KSA + ks) * 64 + row) * 128 + d4];
            const float f = sf[ks][row];
            a0 = fmaf(f, bf2f(sp.x), a0);
            a1 = fmaf(f, bf2f(sp.y), a1);
            a2 = fmaf(f, bf2f(sp.z), a2);
            a3 = fmaf(f, bf2f(sp.w), a3);
        }
        const float iL = sinvL[row];
        a0 *= iL; a1 *= iL; a2 *= iL; a3 *= iL;
        const int hh = kvh * 4 + (row >> 4);
        const int tok = b * SEQ + (row & 15);
        const int col = hh * 128 + d4;
        short4 o;
        o.x = f2bf(a0); o.y = f2bf(a1); o.z = f2bf(a2); o.w = f2bf(a3);
        *(short4*)&aob[((size_t)(col >> 3) * 128 + tok) * 8 + (col & 7)] = o;
    }
}

// Sum the KSPLIT bf16 out-proj partials into f32 d_out.
__global__ __launch_bounds__(256) void sum_parts(const short* __restrict__ P,
                                                 float* __restrict__ out) {
    int i = blockIdx.x * 256 + threadIdx.x;     // over groups of 4 elems, 131072 total
    float a0 = 0.f, a1 = 0.f, a2 = 0.f, a3 = 0.f;
#pragma unroll
    for (int ks = 0; ks < KSPLIT; ++ks) {
        const short4 t = ((const short4*)(P + (size_t)ks * NTOK * 4096))[i];
        a0 += bf2f(t.x); a1 += bf2f(t.y); a2 += bf2f(t.z); a3 += bf2f(t.w);
    }
    ((float4*)out)[i] = make_float4(a0, a1, a2, a3);
}

extern "C" void kernel_launch(void* const* d_in, const int* in_sizes, int n_in,
                              void* d_out, int out_size, void* d_ws, size_t ws_size,
                              hipStream_t stream) {
    const float* x  = (const float*)d_in[0];
    const float* wq = (const float*)d_in[1];
    const float* wk = (const float*)d_in[2];
    const float* wv = (const float*)d_in[3];
    const float* wo = (const float*)d_in[4];
    const float* cs = (const float*)d_in[5];
    const float* sn = (const float*)d_in[6];
    const float* ck = (const float*)d_in[7];
    const float* cv = (const float*)d_in[8];
    const int* startp = (const int*)d_in[9];

    // ws layout (bf16 partials). Opart (16.8MB) overlays Pqb+Pkb+Pvb (12.6MB) plus
    // 4.2MB of pad; all live buffers start after Opart's full extent.
    short* Opart = (short*)d_ws;                              // 64*16*64*128 shorts
    short* Pqb = Opart;                                       // dead by attn time
    short* Pkb = Pqb + (size_t)KSPLIT * NTOK * 4096;
    short* Pvb = Pkb + (size_t)KSPLIT * NTOK * 1024;
    float* qb   = (float*)(Opart + (size_t)64 * KSA * 64 * 128);  // after 16.8MB
    float* knb  = qb + (size_t)NTOK * 4096;
    float* vnb  = knb + (size_t)NTOK * 1024;
    short* xpre = (short*)(vnb + (size_t)NTOK * 1024);
    short* aob  = xpre + (size_t)NTOK * 4096;
    float* mpart = (float*)(aob + (size_t)NTOK * 4096);
    float* lpart = mpart + (size_t)64 * KSA * 64;
    // total ws ~22.3MB

    cvt_x<<<512, 256, 0, stream>>>(x, xpre);
    // QKV: 64 Q col-blocks (NT=64) + 16 K + 16 V, x KSPLIT=8
    gemm_mfma<<<dim3(96, KSPLIT), 256, 0, stream>>>(xpre, wq, wk, wv, Pqb, Pkb, Pvb);
    combine_rot<<<1536, 256, 0, stream>>>(Pqb, Pkb, Pvb, qb, knb, vnb, cs, sn, startp);
    attn_fused<<<dim3(KSA, KVH, B_), 256, 0, stream>>>(qb, knb, vnb, ck, cv, Opart, mpart, lpart, startp);
    attn_merge<<<64, 256, 0, stream>>>(Opart, mpart, lpart, aob);
    // out-proj: 64 col-blocks (NT=64) x KSPLIT=8, all take the Q branch (W=wo)
    gemm_mfma<<<dim3(64, KSPLIT), 256, 0, stream>>>(aob, wo, wo, wo, Pqb, Pqb, Pqb);
    sum_parts<<<512, 256, 0, stream>>>(Pqb, (float*)d_out);
}